// Round 2
// baseline (1110.910 us; speedup 1.0000x reference)
//
#include <hip/hip_runtime.h>
#include <hip/hip_bf16.h>

#define N_NODES 40000
#define N_EDGES 320000
#define N_GRAPHS 64
#define IN_DIM 128
#define HID4 256
#define OUT_DIM 128
#define LN_EPS 1e-5f

// ---------------- prep kernels ----------------

__global__ void edge_prep(const float* __restrict__ w,
                          const int* __restrict__ src, const int* __restrict__ dst,
                          float* __restrict__ ew, float* __restrict__ out_deg,
                          float* __restrict__ in_deg) {
    int e = blockIdx.x * 256 + threadIdx.x;
    if (e >= N_EDGES) return;
    float a = w[e * 4 + 0];
    float b = w[e * 4 + 1];
    float c = w[e * 4 + 2];
    float d = w[e * 4 + 3];
    ew[e] = fmaxf(fmaxf(a, b), fmaxf(c, d));
    atomicAdd(&out_deg[src[e]], 1.0f);
    atomicAdd(&in_deg[dst[e]], 1.0f);
}

__global__ void node_prep(float* __restrict__ out_inv, float* __restrict__ in_inv) {
    int i = blockIdx.x * 256 + threadIdx.x;
    if (i >= N_NODES) return;
    out_inv[i] = rsqrtf(fmaxf(out_inv[i], 1.0f));
    in_inv[i] = rsqrtf(fmaxf(in_inv[i], 1.0f));
}

// a[idx] = relu(a[idx] * s[idx>>shift])
__global__ void scale_relu_k(float* __restrict__ a, const float* __restrict__ s, int shift) {
    int idx = blockIdx.x * 256 + threadIdx.x;
    a[idx] = fmaxf(a[idx] * s[idx >> shift], 0.0f);
}

// ---------------- edge scatter (wave per edge) ----------------
// agg[dst] += rowScale(src) * ew * h[src]
// rowScale: optional per-src-row scale (out_inv for conv1 where h = raw x)

template <int D>
__global__ void scatter_edges(const float* __restrict__ h, const float* __restrict__ ew,
                              const int* __restrict__ src, const int* __restrict__ dst,
                              const float* __restrict__ rowScale,
                              float* __restrict__ agg) {
    int wv = (blockIdx.x * 256 + threadIdx.x) >> 6;
    int lane = threadIdx.x & 63;
    if (wv >= N_EDGES) return;
    int s = src[wv], d = dst[wv];
    float wgt = ew[wv];
    if (rowScale) wgt *= rowScale[s];
    const float* hs = h + (size_t)s * D;
    float* ad = agg + (size_t)d * D;
#pragma unroll
    for (int i = 0; i < D / 64; ++i)
        atomicAdd(&ad[lane + 64 * i], hs[lane + 64 * i] * wgt);
}

// ---------------- fused fp32 GEMM ----------------
// C[M,N] = epilogue( (rowScaleA ⊙ [A | A2]) @ [B ; B2] )
// A:[M,K1], A2:[M,K2] (may be null, K2=0), B:[K1,N], B2:[K2,N]
// epilogue: optional rowScaleC per-row multiply, optional relu.

#define BM 64
#define BN 64
#define BK 16

__global__ __launch_bounds__(256) void gemm_fused(
    const float* __restrict__ A, const float* __restrict__ A2,
    const float* __restrict__ B, const float* __restrict__ B2,
    float* __restrict__ C,
    const float* __restrict__ rowScaleA, const float* __restrict__ rowScaleC,
    int M, int N, int K1, int K2, int relu) {
    __shared__ float As[BK][BM];
    __shared__ float Bs[BK][BN];
    int m0 = blockIdx.x * BM;
    int n0 = blockIdx.y * BN;
    int tid = threadIdx.x;
    int tr = tid >> 4, tc = tid & 15;
    float acc[4][4] = {};
    int K = K1 + K2;

    int la_m = tid >> 2;         // 0..63
    int la_k = (tid & 3) * 4;    // 0,4,8,12
    int lb_k = tid >> 4;         // 0..15
    int lb_n = (tid & 15) * 4;   // 0..60

    float sA = rowScaleA ? rowScaleA[m0 + la_m] : 1.0f;

    for (int k0 = 0; k0 < K; k0 += BK) {
#pragma unroll
        for (int q = 0; q < 4; ++q) {
            int kk = k0 + la_k + q;
            float v;
            if (kk < K1) v = A[(size_t)(m0 + la_m) * K1 + kk];
            else         v = A2[(size_t)(m0 + la_m) * K2 + (kk - K1)];
            As[la_k + q][la_m] = v * sA;
        }
        {
            int kk = k0 + lb_k;
            const float* Bp = (kk < K1) ? (B + (size_t)kk * N + n0 + lb_n)
                                        : (B2 + (size_t)(kk - K1) * N + n0 + lb_n);
#pragma unroll
            for (int q = 0; q < 4; ++q) Bs[lb_k][lb_n + q] = Bp[q];
        }
        __syncthreads();
#pragma unroll
        for (int k = 0; k < BK; ++k) {
            float ra[4], rb[4];
#pragma unroll
            for (int i = 0; i < 4; ++i) ra[i] = As[k][tr * 4 + i];
#pragma unroll
            for (int j = 0; j < 4; ++j) rb[j] = Bs[k][tc * 4 + j];
#pragma unroll
            for (int i = 0; i < 4; ++i)
#pragma unroll
                for (int j = 0; j < 4; ++j) acc[i][j] += ra[i] * rb[j];
        }
        __syncthreads();
    }

#pragma unroll
    for (int i = 0; i < 4; ++i) {
        int m = m0 + tr * 4 + i;
        float sc = rowScaleC ? rowScaleC[m] : 1.0f;
#pragma unroll
        for (int j = 0; j < 4; ++j) {
            float v = acc[i][j] * sc;
            if (relu) v = fmaxf(v, 0.0f);
            C[(size_t)m * N + n0 + tc * 4 + j] = v;
        }
    }
}

// ---------------- LayerNorm + ReLU (wave per row, 256 cols) ----------------

__global__ void ln_relu_k(float* __restrict__ f, const float* __restrict__ gamma,
                          const float* __restrict__ beta) {
    int row = (blockIdx.x * 256 + threadIdx.x) >> 6;
    int lane = threadIdx.x & 63;
    if (row >= N_NODES) return;
    float4* fr = (float4*)(f + (size_t)row * HID4);
    float4 v = fr[lane];
    float sum = v.x + v.y + v.z + v.w;
#pragma unroll
    for (int m = 1; m < 64; m <<= 1) sum += __shfl_xor(sum, m);
    float mu = sum * (1.0f / HID4);
    float dx = v.x - mu, dy = v.y - mu, dz = v.z - mu, dw = v.w - mu;
    float sq = dx * dx + dy * dy + dz * dz + dw * dw;
#pragma unroll
    for (int m = 1; m < 64; m <<= 1) sq += __shfl_xor(sq, m);
    float rs = rsqrtf(sq * (1.0f / HID4) + LN_EPS);
    int c = lane * 4;
    v.x = fmaxf(dx * rs * gamma[c + 0] + beta[c + 0], 0.0f);
    v.y = fmaxf(dy * rs * gamma[c + 1] + beta[c + 1], 0.0f);
    v.z = fmaxf(dz * rs * gamma[c + 2] + beta[c + 2], 0.0f);
    v.w = fmaxf(dw * rs * gamma[c + 3] + beta[c + 3], 0.0f);
    fr[lane] = v;
}

// ---------------- readout: segment-sum over sorted graph_ids ----------------

#define NODES_PER_BLOCK 250

__global__ void readout_sum(const float* __restrict__ x3, const int* __restrict__ gid,
                            float* __restrict__ ro) {
    int d = threadIdx.x;  // 0..127
    int n0 = blockIdx.x * NODES_PER_BLOCK;
    int n1 = n0 + NODES_PER_BLOCK;
    if (n1 > N_NODES) n1 = N_NODES;
    float acc = 0.0f;
    int cur = gid[n0];
    for (int n = n0; n < n1; ++n) {
        int g = gid[n];
        if (g != cur) {
            atomicAdd(&ro[cur * OUT_DIM + d], acc);
            acc = 0.0f;
            cur = g;
        }
        acc += x3[(size_t)n * OUT_DIM + d];
    }
    atomicAdd(&ro[cur * OUT_DIM + d], acc);
}

__global__ void normalize_out(const float* __restrict__ ro, float* __restrict__ out) {
    int g = blockIdx.x;
    int d = threadIdx.x;  // 128 threads = 2 waves
    float v = ro[g * OUT_DIM + d];
    float ss = v * v;
#pragma unroll
    for (int m = 1; m < 64; m <<= 1) ss += __shfl_xor(ss, m);
    __shared__ float s2[2];
    if ((d & 63) == 0) s2[d >> 6] = ss;
    __syncthreads();
    float tot = s2[0] + s2[1];
    float norm = fmaxf(sqrtf(tot), 1e-12f);
    out[g * OUT_DIM + d] = v / norm;
}

// ---------------- launch ----------------

extern "C" void kernel_launch(void* const* d_in, const int* in_sizes, int n_in,
                              void* d_out, int out_size, void* d_ws, size_t ws_size,
                              hipStream_t stream) {
    const float* x    = (const float*)d_in[0];
    const float* w    = (const float*)d_in[1];
    const float* W1   = (const float*)d_in[2];
    const float* fc1W = (const float*)d_in[3];
    const float* gam  = (const float*)d_in[4];
    const float* bet  = (const float*)d_in[5];
    const float* W2   = (const float*)d_in[6];
    const float* W3   = (const float*)d_in[7];
    const int* src = (const int*)d_in[8];
    const int* dst = (const int*)d_in[9];
    const int* gid = (const int*)d_in[10];
    float* out = (float*)d_out;

    float* ws = (float*)d_ws;
    // workspace layout (float offsets); total span 31,140,000 floats ≈ 124.6 MB
    float* out_inv = ws + 0;          // 40000
    float* in_inv  = ws + 40000;      // 40000
    float* ew      = ws + 80000;      // 320000
    float* ro      = ws + 400000;     // 8192
    float* regA    = ws + 420000;     // 10.24M : x1 -> agg2/x2
    float* regB    = ws + 10660000;   // 10.24M : f1 -> Q3 (first 5.12M)
    float* regC    = ws + 20900000;   // 10.24M : agg1 (first 5.12M) -> P2 -> agg3/x3 (first 5.12M)

    float* agg1 = regC;
    float* x1   = regA;
    float* f1   = regB;
    float* P2   = regC;
    float* agg2 = regA;   // x2 in place
    float* Q3   = regB;
    float* agg3 = regC;   // x3 in place

    // --- zero degree arrays / agg1 / readout ---
    hipMemsetAsync(out_inv, 0, 2 * 40000 * sizeof(float), stream);   // out_inv + in_inv adjacent
    hipMemsetAsync(ro, 0, (size_t)N_GRAPHS * OUT_DIM * sizeof(float), stream);
    hipMemsetAsync(agg1, 0, (size_t)N_NODES * IN_DIM * sizeof(float), stream);

    // --- degrees & edge weights ---
    edge_prep<<<(N_EDGES + 255) / 256, 256, 0, stream>>>(w, src, dst, ew, out_inv, in_inv);
    node_prep<<<(N_NODES + 255) / 256, 256, 0, stream>>>(out_inv, in_inv);

    // --- conv1: agg1 = scatter(ew * out_inv[src] * x[src]); x1 = relu((in_inv⊙agg1)@W1) ---
    scatter_edges<IN_DIM><<<N_EDGES / 4, 256, 0, stream>>>(x, ew, src, dst, out_inv, agg1);
    {
        dim3 grid(N_NODES / BM, HID4 / BN);
        gemm_fused<<<grid, 256, 0, stream>>>(agg1, nullptr, W1, nullptr, x1,
                                             in_inv, nullptr, N_NODES, HID4, IN_DIM, 0, 1);
    }

    // --- fc1 branch: f1 = relu(LN(x @ fc1_W)) ---
    {
        dim3 grid(N_NODES / BM, HID4 / BN);
        gemm_fused<<<grid, 256, 0, stream>>>(x, nullptr, fc1W, nullptr, f1,
                                             nullptr, nullptr, N_NODES, HID4, IN_DIM, 0, 0);
    }
    ln_relu_k<<<N_NODES / 4, 256, 0, stream>>>(f1, gam, bet);

    // --- conv2 (matmul first): P2 = (x1@W2_top + f1@W2_bot) ⊙ out_inv ---
    {
        dim3 grid(N_NODES / BM, HID4 / BN);
        gemm_fused<<<grid, 256, 0, stream>>>(x1, f1, W2, W2 + (size_t)HID4 * HID4, P2,
                                             nullptr, out_inv, N_NODES, HID4, HID4, HID4, 0);
    }
    hipMemsetAsync(agg2, 0, (size_t)N_NODES * HID4 * sizeof(float), stream);
    scatter_edges<HID4><<<N_EDGES / 4, 256, 0, stream>>>(P2, ew, src, dst, nullptr, agg2);
    // x2 = relu(agg2 * in_inv) in place
    scale_relu_k<<<N_NODES * HID4 / 256, 256, 0, stream>>>(agg2, in_inv, 8);

    // --- conv3 (matmul first): Q3 = (x2 @ W3) ⊙ out_inv ---
    {
        dim3 grid(N_NODES / BM, OUT_DIM / BN);
        gemm_fused<<<grid, 256, 0, stream>>>(agg2, nullptr, W3, nullptr, Q3,
                                             nullptr, out_inv, N_NODES, OUT_DIM, HID4, 0, 0);
    }
    hipMemsetAsync(agg3, 0, (size_t)N_NODES * OUT_DIM * sizeof(float), stream);
    scatter_edges<OUT_DIM><<<N_EDGES / 4, 256, 0, stream>>>(Q3, ew, src, dst, nullptr, agg3);
    // x3 = relu(agg3 * in_inv) in place
    scale_relu_k<<<N_NODES * OUT_DIM / 256, 256, 0, stream>>>(agg3, in_inv, 7);

    // --- readout + normalize ---
    readout_sum<<<(N_NODES + NODES_PER_BLOCK - 1) / NODES_PER_BLOCK, 128, 0, stream>>>(agg3, gid, ro);
    normalize_out<<<N_GRAPHS, 128, 0, stream>>>(ro, out);
}

// Round 3
// 707.738 us; speedup vs baseline: 1.5697x; 1.5697x over previous
//
#include <hip/hip_runtime.h>
#include <hip/hip_bf16.h>

#define N_NODES 40000
#define N_EDGES 320000
#define N_GRAPHS 64
#define IN_DIM 128
#define HID4 256
#define OUT_DIM 128
#define LN_EPS 1e-5f

// ---------------- prep kernels ----------------

__global__ void edge_prep(const float* __restrict__ w, const int* __restrict__ src,
                          const int* __restrict__ dst, float* __restrict__ ew,
                          int* __restrict__ cnt_out, int* __restrict__ cnt_in) {
    int e = blockIdx.x * 256 + threadIdx.x;
    if (e >= N_EDGES) return;
    float4 v = ((const float4*)w)[e];
    ew[e] = fmaxf(fmaxf(v.x, v.y), fmaxf(v.z, v.w));
    atomicAdd(&cnt_out[src[e]], 1);
    atomicAdd(&cnt_in[dst[e]], 1);
}

__global__ void node_prep(const int* __restrict__ cnt_out, const int* __restrict__ cnt_in,
                          float* __restrict__ out_inv, float* __restrict__ in_inv) {
    int i = blockIdx.x * 256 + threadIdx.x;
    if (i >= N_NODES) return;
    out_inv[i] = rsqrtf(fmaxf((float)cnt_out[i], 1.0f));
    in_inv[i] = rsqrtf(fmaxf((float)cnt_in[i], 1.0f));
}

// single-block exclusive scan over cnt_in -> off[0..N_NODES]
__global__ void scan_offsets(const int* __restrict__ cnt, int* __restrict__ off) {
    __shared__ int wsum[16];
    __shared__ int carry_s;
    int tid = threadIdx.x;
    int lane = tid & 63, wv = tid >> 6;
    if (tid == 0) carry_s = 0;
    __syncthreads();
    for (int base = 0; base < N_NODES; base += 1024) {
        int i = base + tid;
        int v = (i < N_NODES) ? cnt[i] : 0;
        int x = v;
#pragma unroll
        for (int ofs = 1; ofs < 64; ofs <<= 1) {
            int t = __shfl_up(x, ofs);
            if (lane >= ofs) x += t;
        }
        if (lane == 63) wsum[wv] = x;
        __syncthreads();
        if (wv == 0 && lane < 16) {
            int s = wsum[lane];
#pragma unroll
            for (int ofs = 1; ofs < 16; ofs <<= 1) {
                int t = __shfl_up(s, ofs);
                if (lane >= ofs) s += t;
            }
            wsum[lane] = s;  // inclusive wave-sum scan
        }
        __syncthreads();
        int prefix = carry_s + (wv > 0 ? wsum[wv - 1] : 0);
        int incl = prefix + x;
        if (i < N_NODES) off[i] = incl - v;  // exclusive
        __syncthreads();
        if (tid == 1023) carry_s = incl;
        __syncthreads();
    }
    if (tid == 0) off[N_NODES] = carry_s;
}

// slot-fill: group edges by dst; store src, ew, and ew*out_inv[src] permuted
__global__ void csr_fill(const int* __restrict__ src, const int* __restrict__ dst,
                         const float* __restrict__ ew, const float* __restrict__ out_inv,
                         const int* __restrict__ off, int* __restrict__ cursor,
                         int* __restrict__ srcs, float* __restrict__ ewp,
                         float* __restrict__ ewps) {
    int e = blockIdx.x * 256 + threadIdx.x;
    if (e >= N_EDGES) return;
    int d = dst[e];
    int slot = off[d] + atomicAdd(&cursor[d], 1);
    int s = src[e];
    float wv = ew[e];
    srcs[slot] = s;
    ewp[slot] = wv;
    ewps[slot] = wv * out_inv[s];
}

// ---------------- gather aggregation (block per dst node) ----------------
// outb[n] = maybe_relu( scale[n] * sum_{e in CSR(n)} ews[e] * h[srcs[e]] )

template <int D, int RELU>
__global__ void gather_nodes(const float* __restrict__ h, const int* __restrict__ off,
                             const int* __restrict__ srcs, const float* __restrict__ ews,
                             const float* __restrict__ scale, float* __restrict__ outb) {
    int n = blockIdx.x;
    int t = threadIdx.x;  // D threads
    int b = off[n], e = off[n + 1];
    float acc = 0.0f;
    int i = b;
    for (; i + 1 < e; i += 2) {
        int s0 = srcs[i], s1 = srcs[i + 1];
        float w0 = ews[i], w1 = ews[i + 1];
        acc += w0 * h[(size_t)s0 * D + t] + w1 * h[(size_t)s1 * D + t];
    }
    if (i < e) acc += ews[i] * h[(size_t)srcs[i] * D + t];
    float v = acc * scale[n];
    if (RELU) v = fmaxf(v, 0.0f);
    outb[(size_t)n * D + t] = v;
}

// ---------------- fused fp32 GEMM ----------------
// C[M,N] = epilogue( [A | A2] @ [B ; B2] ), optional rowScaleC, optional relu

#define BM 64
#define BN 64
#define BK 16

__global__ __launch_bounds__(256) void gemm_fused(
    const float* __restrict__ A, const float* __restrict__ A2,
    const float* __restrict__ B, const float* __restrict__ B2,
    float* __restrict__ C,
    const float* __restrict__ rowScaleC,
    int M, int N, int K1, int K2, int relu) {
    __shared__ float As[BK][BM];
    __shared__ float Bs[BK][BN];
    int m0 = blockIdx.x * BM;
    int n0 = blockIdx.y * BN;
    int tid = threadIdx.x;
    int tr = tid >> 4, tc = tid & 15;
    float acc[4][4] = {};
    int K = K1 + K2;

    int la_m = tid >> 2;         // 0..63
    int la_k = (tid & 3) * 4;    // 0,4,8,12
    int lb_k = tid >> 4;         // 0..15
    int lb_n = (tid & 15) * 4;   // 0..60

    for (int k0 = 0; k0 < K; k0 += BK) {
#pragma unroll
        for (int q = 0; q < 4; ++q) {
            int kk = k0 + la_k + q;
            float v;
            if (kk < K1) v = A[(size_t)(m0 + la_m) * K1 + kk];
            else         v = A2[(size_t)(m0 + la_m) * K2 + (kk - K1)];
            As[la_k + q][la_m] = v;
        }
        {
            int kk = k0 + lb_k;
            const float* Bp = (kk < K1) ? (B + (size_t)kk * N + n0 + lb_n)
                                        : (B2 + (size_t)(kk - K1) * N + n0 + lb_n);
#pragma unroll
            for (int q = 0; q < 4; ++q) Bs[lb_k][lb_n + q] = Bp[q];
        }
        __syncthreads();
#pragma unroll
        for (int k = 0; k < BK; ++k) {
            float ra[4], rb[4];
#pragma unroll
            for (int i = 0; i < 4; ++i) ra[i] = As[k][tr * 4 + i];
#pragma unroll
            for (int j = 0; j < 4; ++j) rb[j] = Bs[k][tc * 4 + j];
#pragma unroll
            for (int i = 0; i < 4; ++i)
#pragma unroll
                for (int j = 0; j < 4; ++j) acc[i][j] += ra[i] * rb[j];
        }
        __syncthreads();
    }

#pragma unroll
    for (int i = 0; i < 4; ++i) {
        int m = m0 + tr * 4 + i;
        float sc = rowScaleC ? rowScaleC[m] : 1.0f;
#pragma unroll
        for (int j = 0; j < 4; ++j) {
            float v = acc[i][j] * sc;
            if (relu) v = fmaxf(v, 0.0f);
            C[(size_t)m * N + n0 + tc * 4 + j] = v;
        }
    }
}

// ---------------- LayerNorm + ReLU (wave per row, 256 cols) ----------------

__global__ void ln_relu_k(float* __restrict__ f, const float* __restrict__ gamma,
                          const float* __restrict__ beta) {
    int row = (blockIdx.x * 256 + threadIdx.x) >> 6;
    int lane = threadIdx.x & 63;
    if (row >= N_NODES) return;
    float4* fr = (float4*)(f + (size_t)row * HID4);
    float4 v = fr[lane];
    float sum = v.x + v.y + v.z + v.w;
#pragma unroll
    for (int m = 1; m < 64; m <<= 1) sum += __shfl_xor(sum, m);
    float mu = sum * (1.0f / HID4);
    float dx = v.x - mu, dy = v.y - mu, dz = v.z - mu, dw = v.w - mu;
    float sq = dx * dx + dy * dy + dz * dz + dw * dw;
#pragma unroll
    for (int m = 1; m < 64; m <<= 1) sq += __shfl_xor(sq, m);
    float rs = rsqrtf(sq * (1.0f / HID4) + LN_EPS);
    int c = lane * 4;
    v.x = fmaxf(dx * rs * gamma[c + 0] + beta[c + 0], 0.0f);
    v.y = fmaxf(dy * rs * gamma[c + 1] + beta[c + 1], 0.0f);
    v.z = fmaxf(dz * rs * gamma[c + 2] + beta[c + 2], 0.0f);
    v.w = fmaxf(dw * rs * gamma[c + 3] + beta[c + 3], 0.0f);
    fr[lane] = v;
}

// ---------------- readout ----------------

#define NODES_PER_BLOCK 250

__global__ void readout_sum(const float* __restrict__ x3, const int* __restrict__ gid,
                            float* __restrict__ ro) {
    int d = threadIdx.x;  // 0..127
    int n0 = blockIdx.x * NODES_PER_BLOCK;
    int n1 = n0 + NODES_PER_BLOCK;
    if (n1 > N_NODES) n1 = N_NODES;
    float acc = 0.0f;
    int cur = gid[n0];
    for (int n = n0; n < n1; ++n) {
        int g = gid[n];
        if (g != cur) {
            atomicAdd(&ro[cur * OUT_DIM + d], acc);
            acc = 0.0f;
            cur = g;
        }
        acc += x3[(size_t)n * OUT_DIM + d];
    }
    atomicAdd(&ro[cur * OUT_DIM + d], acc);
}

__global__ void normalize_out(const float* __restrict__ ro, float* __restrict__ out) {
    int g = blockIdx.x;
    int d = threadIdx.x;  // 128 threads = 2 waves
    float v = ro[g * OUT_DIM + d];
    float ss = v * v;
#pragma unroll
    for (int m = 1; m < 64; m <<= 1) ss += __shfl_xor(ss, m);
    __shared__ float s2[2];
    if ((d & 63) == 0) s2[d >> 6] = ss;
    __syncthreads();
    float tot = s2[0] + s2[1];
    float norm = fmaxf(sqrtf(tot), 1e-12f);
    out[g * OUT_DIM + d] = v / norm;
}

// ---------------- launch ----------------

extern "C" void kernel_launch(void* const* d_in, const int* in_sizes, int n_in,
                              void* d_out, int out_size, void* d_ws, size_t ws_size,
                              hipStream_t stream) {
    const float* x    = (const float*)d_in[0];
    const float* w    = (const float*)d_in[1];
    const float* W1   = (const float*)d_in[2];
    const float* fc1W = (const float*)d_in[3];
    const float* gam  = (const float*)d_in[4];
    const float* bet  = (const float*)d_in[5];
    const float* W2   = (const float*)d_in[6];
    const float* W3   = (const float*)d_in[7];
    const int* src = (const int*)d_in[8];
    const int* dst = (const int*)d_in[9];
    const int* gid = (const int*)d_in[10];
    float* out = (float*)d_out;

    float* ws = (float*)d_ws;
    // workspace layout (float-sized slots); span ~32.27M floats ~= 129 MB
    float* out_inv = ws + 0;          // 40000
    float* in_inv  = ws + 40000;      // 40000
    float* ew      = ws + 80000;      // 320000
    float* ro      = ws + 400000;     // 8192
    float* regA    = ws + 420000;     // 10.24M : x1 -> x2
    float* regB    = ws + 10660000;   // 10.24M : f1 -> Q3
    float* regC    = ws + 20900000;   // 10.24M : agg1 -> P2 -> x3
    int*   cnt_out = (int*)(ws + 31140000);   // 40000
    int*   cnt_in  = (int*)(ws + 31180000);   // 40000
    int*   cursor  = (int*)(ws + 31220000);   // 40000
    int*   off     = (int*)(ws + 31260000);   // 40001
    int*   srcs    = (int*)(ws + 31300002);   // 320000
    float* ewp     = ws + 31620002;           // 320000
    float* ewps    = ws + 31940002;           // 320000

    float* agg1 = regC;
    float* x1   = regA;
    float* f1   = regB;
    float* P2   = regC;
    float* x2   = regA;
    float* Q3   = regB;
    float* x3   = regC;

    // --- zero histogram/cursor (contiguous) + readout accumulator ---
    hipMemsetAsync(cnt_out, 0, 3 * 40000 * sizeof(int), stream);
    hipMemsetAsync(ro, 0, (size_t)N_GRAPHS * OUT_DIM * sizeof(float), stream);

    // --- degrees, edge weights, CSR ---
    edge_prep<<<(N_EDGES + 255) / 256, 256, 0, stream>>>(w, src, dst, ew, cnt_out, cnt_in);
    node_prep<<<(N_NODES + 255) / 256, 256, 0, stream>>>(cnt_out, cnt_in, out_inv, in_inv);
    scan_offsets<<<1, 1024, 0, stream>>>(cnt_in, off);
    csr_fill<<<(N_EDGES + 255) / 256, 256, 0, stream>>>(src, dst, ew, out_inv, off, cursor,
                                                        srcs, ewp, ewps);

    // --- conv1: agg1 = in_inv ⊙ gather(ew*out_inv[src] * x[src]); x1 = relu(agg1 @ W1) ---
    gather_nodes<IN_DIM, 0><<<N_NODES, IN_DIM, 0, stream>>>(x, off, srcs, ewps, in_inv, agg1);
    {
        dim3 grid(N_NODES / BM, HID4 / BN);
        gemm_fused<<<grid, 256, 0, stream>>>(agg1, nullptr, W1, nullptr, x1,
                                             nullptr, N_NODES, HID4, IN_DIM, 0, 1);
    }

    // --- fc1 branch: f1 = relu(LN(x @ fc1_W)) ---
    {
        dim3 grid(N_NODES / BM, HID4 / BN);
        gemm_fused<<<grid, 256, 0, stream>>>(x, nullptr, fc1W, nullptr, f1,
                                             nullptr, N_NODES, HID4, IN_DIM, 0, 0);
    }
    ln_relu_k<<<N_NODES / 4, 256, 0, stream>>>(f1, gam, bet);

    // --- conv2 (matmul first): P2 = (x1@W2_top + f1@W2_bot) ⊙ out_inv ; x2 = relu(in_inv ⊙ gather(ew*P2[src])) ---
    {
        dim3 grid(N_NODES / BM, HID4 / BN);
        gemm_fused<<<grid, 256, 0, stream>>>(x1, f1, W2, W2 + (size_t)HID4 * HID4, P2,
                                             out_inv, N_NODES, HID4, HID4, HID4, 0);
    }
    gather_nodes<HID4, 1><<<N_NODES, HID4, 0, stream>>>(P2, off, srcs, ewp, in_inv, x2);

    // --- conv3: Q3 = (x2 @ W3) ⊙ out_inv ; x3 = relu(in_inv ⊙ gather(ew*Q3[src])) ---
    {
        dim3 grid(N_NODES / BM, OUT_DIM / BN);
        gemm_fused<<<grid, 256, 0, stream>>>(x2, nullptr, W3, nullptr, Q3,
                                             out_inv, N_NODES, OUT_DIM, HID4, 0, 0);
    }
    gather_nodes<OUT_DIM, 1><<<N_NODES, OUT_DIM, 0, stream>>>(Q3, off, srcs, ewp, in_inv, x3);

    // --- readout + normalize ---
    readout_sum<<<(N_NODES + NODES_PER_BLOCK - 1) / NODES_PER_BLOCK, 128, 0, stream>>>(x3, gid, ro);
    normalize_out<<<N_GRAPHS, 128, 0, stream>>>(ro, out);
}

// Round 4
// 457.298 us; speedup vs baseline: 2.4293x; 1.5477x over previous
//
#include <hip/hip_runtime.h>

#define N_NODES 40000
#define M_PAD   40064   // 313 * 128
#define N_EDGES 320000
#define N_GRAPHS 64
#define IN_DIM 128
#define HID4 256
#define OUT_DIM 128
#define LN_EPS 1e-5f

typedef short  s16x8  __attribute__((ext_vector_type(8)));
typedef short  s16x4  __attribute__((ext_vector_type(4)));
typedef __bf16 bf16x8 __attribute__((ext_vector_type(8)));
typedef float  f32x4  __attribute__((ext_vector_type(4)));

__device__ __forceinline__ unsigned short f2b(float f) {
    unsigned int u = __builtin_bit_cast(unsigned int, f);
    u += 0x7fffu + ((u >> 16) & 1u);   // round-to-nearest-even
    return (unsigned short)(u >> 16);
}
__device__ __forceinline__ float b2f(unsigned short h) {
    unsigned int u = (unsigned int)h << 16;
    return __builtin_bit_cast(float, u);
}

// ---------------- prep kernels ----------------

__global__ void edge_prep(const float* __restrict__ w, const int* __restrict__ src,
                          const int* __restrict__ dst, float* __restrict__ ew,
                          int* __restrict__ cnt_out, int* __restrict__ cnt_in) {
    int e = blockIdx.x * 256 + threadIdx.x;
    if (e >= N_EDGES) return;
    float4 v = ((const float4*)w)[e];
    ew[e] = fmaxf(fmaxf(v.x, v.y), fmaxf(v.z, v.w));
    atomicAdd(&cnt_out[src[e]], 1);
    atomicAdd(&cnt_in[dst[e]], 1);
}

__global__ void node_prep(const int* __restrict__ cnt_out, const int* __restrict__ cnt_in,
                          float* __restrict__ out_inv, float* __restrict__ in_inv) {
    int i = blockIdx.x * 256 + threadIdx.x;
    if (i >= N_NODES) return;
    out_inv[i] = rsqrtf(fmaxf((float)cnt_out[i], 1.0f));
    in_inv[i] = rsqrtf(fmaxf((float)cnt_in[i], 1.0f));
}

// single-block exclusive scan over cnt -> off[0..N_NODES]
__global__ void scan_offsets(const int* __restrict__ cnt, int* __restrict__ off) {
    __shared__ int wsum[16];
    __shared__ int carry_s;
    int tid = threadIdx.x;
    int lane = tid & 63, wv = tid >> 6;
    if (tid == 0) carry_s = 0;
    __syncthreads();
    for (int base = 0; base < N_NODES; base += 1024) {
        int i = base + tid;
        int v = (i < N_NODES) ? cnt[i] : 0;
        int x = v;
#pragma unroll
        for (int ofs = 1; ofs < 64; ofs <<= 1) {
            int t = __shfl_up(x, ofs);
            if (lane >= ofs) x += t;
        }
        if (lane == 63) wsum[wv] = x;
        __syncthreads();
        if (wv == 0 && lane < 16) {
            int s = wsum[lane];
#pragma unroll
            for (int ofs = 1; ofs < 16; ofs <<= 1) {
                int t = __shfl_up(s, ofs);
                if (lane >= ofs) s += t;
            }
            wsum[lane] = s;
        }
        __syncthreads();
        int prefix = carry_s + (wv > 0 ? wsum[wv - 1] : 0);
        int incl = prefix + x;
        if (i < N_NODES) off[i] = incl - v;
        __syncthreads();
        if (tid == 1023) carry_s = incl;
        __syncthreads();
    }
    if (tid == 0) off[N_NODES] = carry_s;
}

__global__ void csr_fill(const int* __restrict__ src, const int* __restrict__ dst,
                         const float* __restrict__ ew, const float* __restrict__ out_inv,
                         const int* __restrict__ off, int* __restrict__ cursor,
                         int* __restrict__ srcs, float* __restrict__ ewp,
                         float* __restrict__ ewps) {
    int e = blockIdx.x * 256 + threadIdx.x;
    if (e >= N_EDGES) return;
    int d = dst[e];
    int slot = off[d] + atomicAdd(&cursor[d], 1);
    int s = src[e];
    float wv = ew[e];
    srcs[slot] = s;
    ewp[slot] = wv;
    ewps[slot] = wv * out_inv[s];
}

// ---------------- conversions ----------------

__global__ void cvt_f32_bf16(const float* __restrict__ in, unsigned short* __restrict__ out, int n) {
    int i = blockIdx.x * 256 + threadIdx.x;
    if (i < n) out[i] = f2b(in[i]);
}

// in: [K][N] fp32 row-major ; outT: [N][K] bf16
__global__ void transpose_cvt(const float* __restrict__ in, unsigned short* __restrict__ outT,
                              int K, int N) {
    int idx = blockIdx.x * 256 + threadIdx.x;
    if (idx >= K * N) return;
    int k = idx / N, n = idx - k * N;
    outT[(size_t)n * K + k] = f2b(in[idx]);
}

// ---------------- gather aggregation (block per dst node), bf16 in ----------------

template <int D, int RELU, int OUT_BF16>
__global__ void gather_nodes(const unsigned short* __restrict__ h, const int* __restrict__ off,
                             const int* __restrict__ srcs, const float* __restrict__ ews,
                             const float* __restrict__ scale, void* __restrict__ outp) {
    int n = blockIdx.x;
    int t = threadIdx.x;  // D threads
    int b = off[n], e = off[n + 1];
    float acc = 0.0f;
    int i = b;
    for (; i + 1 < e; i += 2) {
        int s0 = srcs[i], s1 = srcs[i + 1];
        float w0 = ews[i], w1 = ews[i + 1];
        acc += w0 * b2f(h[(size_t)s0 * D + t]) + w1 * b2f(h[(size_t)s1 * D + t]);
    }
    if (i < e) acc += ews[i] * b2f(h[(size_t)srcs[i] * D + t]);
    float v = acc * scale[n];
    if (RELU) v = fmaxf(v, 0.0f);
    if (OUT_BF16) ((unsigned short*)outp)[(size_t)n * D + t] = f2b(v);
    else          ((float*)outp)[(size_t)n * D + t] = v;
}

// ---------------- MFMA bf16 GEMM ----------------
// C[M_PAD][N] (bf16) = epilogue( [A | A2] @ Bt^T ), A:[M_PAD][K1], A2:[M_PAD][K2] bf16,
// Bt:[N][K] bf16 (pre-transposed weights). Block tile 128x128, BK=32, 4 waves.

template <int RELU, int SCALE_C>
__global__ __launch_bounds__(256) void gemm_mfma(
    const unsigned short* __restrict__ A, const unsigned short* __restrict__ A2,
    const unsigned short* __restrict__ Bt, unsigned short* __restrict__ C,
    const float* __restrict__ rowScaleC, int K1, int K2, int N) {
    __shared__ short As[128][40];   // [m][k] +8 pad -> 2-way-max bank aliasing
    __shared__ short Bs[128][40];   // [n][k]
    const int K = K1 + K2;
    int tid = threadIdx.x;
    int lane = tid & 63, wave = tid >> 6;
    int wm = (wave >> 1) * 64, wn = (wave & 1) * 64;
    int quad = lane >> 4, r16 = lane & 15;
    int m0 = blockIdx.x * 128, n0 = blockIdx.y * 128;

    f32x4 acc[4][4] = {};

    int ra = tid >> 2;        // 0..63
    int ca = (tid & 3) * 8;   // k-chunk within 32 (8 bf16 = 16B)

    for (int k0 = 0; k0 < K; k0 += 32) {
#pragma unroll
        for (int h = 0; h < 2; ++h) {
            int r = ra + h * 64;
            int kk = k0 + ca;
            const unsigned short* Ap = (kk < K1)
                ? A  + (size_t)(m0 + r) * K1 + kk
                : A2 + (size_t)(m0 + r) * K2 + (kk - K1);
            *(s16x8*)&As[r][ca] = *(const s16x8*)Ap;
            *(s16x8*)&Bs[r][ca] = *(const s16x8*)(Bt + (size_t)(n0 + r) * K + kk);
        }
        __syncthreads();
        s16x8 af[4], bfr[4];
#pragma unroll
        for (int i = 0; i < 4; ++i) af[i]  = *(const s16x8*)&As[wm + i * 16 + r16][quad * 8];
#pragma unroll
        for (int j = 0; j < 4; ++j) bfr[j] = *(const s16x8*)&Bs[wn + j * 16 + r16][quad * 8];
#pragma unroll
        for (int i = 0; i < 4; ++i)
#pragma unroll
            for (int j = 0; j < 4; ++j)
                acc[i][j] = __builtin_amdgcn_mfma_f32_16x16x32_bf16(
                    __builtin_bit_cast(bf16x8, af[i]), __builtin_bit_cast(bf16x8, bfr[j]),
                    acc[i][j], 0, 0, 0);
        __syncthreads();
    }

    // C/D layout: col = lane&15, row = quad*4 + reg
#pragma unroll
    for (int i = 0; i < 4; ++i) {
        int mbase = m0 + wm + i * 16 + quad * 4;
#pragma unroll
        for (int r = 0; r < 4; ++r) {
            int m = mbase + r;
            float sc = SCALE_C ? rowScaleC[m] : 1.0f;
#pragma unroll
            for (int j = 0; j < 4; ++j) {
                float v = acc[i][j][r] * sc;
                if (RELU) v = fmaxf(v, 0.0f);
                C[(size_t)m * N + n0 + wn + j * 16 + r16] = f2b(v);
            }
        }
    }
}

// ---------------- LayerNorm + ReLU, in-place bf16 (wave per row, 256 cols) ----------------

__global__ void ln_relu_bf16(unsigned short* __restrict__ f, const float* __restrict__ gamma,
                             const float* __restrict__ beta) {
    int row = (blockIdx.x * 256 + threadIdx.x) >> 6;
    int lane = threadIdx.x & 63;
    if (row >= N_NODES) return;
    s16x4* fr = (s16x4*)(f + (size_t)row * HID4);
    s16x4 pv = fr[lane];
    float v0 = b2f((unsigned short)pv[0]);
    float v1 = b2f((unsigned short)pv[1]);
    float v2 = b2f((unsigned short)pv[2]);
    float v3 = b2f((unsigned short)pv[3]);
    float sum = v0 + v1 + v2 + v3;
#pragma unroll
    for (int m = 1; m < 64; m <<= 1) sum += __shfl_xor(sum, m);
    float mu = sum * (1.0f / HID4);
    float d0 = v0 - mu, d1 = v1 - mu, d2 = v2 - mu, d3 = v3 - mu;
    float sq = d0 * d0 + d1 * d1 + d2 * d2 + d3 * d3;
#pragma unroll
    for (int m = 1; m < 64; m <<= 1) sq += __shfl_xor(sq, m);
    float rs = rsqrtf(sq * (1.0f / HID4) + LN_EPS);
    int c = lane * 4;
    s16x4 ov;
    ov[0] = (short)f2b(fmaxf(d0 * rs * gamma[c + 0] + beta[c + 0], 0.0f));
    ov[1] = (short)f2b(fmaxf(d1 * rs * gamma[c + 1] + beta[c + 1], 0.0f));
    ov[2] = (short)f2b(fmaxf(d2 * rs * gamma[c + 2] + beta[c + 2], 0.0f));
    ov[3] = (short)f2b(fmaxf(d3 * rs * gamma[c + 3] + beta[c + 3], 0.0f));
    fr[lane] = ov;
}

// ---------------- readout ----------------

#define NODES_PER_BLOCK 250

__global__ void readout_sum(const float* __restrict__ x3, const int* __restrict__ gid,
                            float* __restrict__ ro) {
    int d = threadIdx.x;  // 0..127
    int n0 = blockIdx.x * NODES_PER_BLOCK;
    int n1 = n0 + NODES_PER_BLOCK;
    if (n1 > N_NODES) n1 = N_NODES;
    float acc = 0.0f;
    int cur = gid[n0];
    for (int n = n0; n < n1; ++n) {
        int g = gid[n];
        if (g != cur) {
            atomicAdd(&ro[cur * OUT_DIM + d], acc);
            acc = 0.0f;
            cur = g;
        }
        acc += x3[(size_t)n * OUT_DIM + d];
    }
    atomicAdd(&ro[cur * OUT_DIM + d], acc);
}

__global__ void normalize_out(const float* __restrict__ ro, float* __restrict__ out) {
    int g = blockIdx.x;
    int d = threadIdx.x;  // 128 threads = 2 waves
    float v = ro[g * OUT_DIM + d];
    float ss = v * v;
#pragma unroll
    for (int m = 1; m < 64; m <<= 1) ss += __shfl_xor(ss, m);
    __shared__ float s2[2];
    if ((d & 63) == 0) s2[d >> 6] = ss;
    __syncthreads();
    float tot = s2[0] + s2[1];
    float norm = fmaxf(sqrtf(tot), 1e-12f);
    out[g * OUT_DIM + d] = v / norm;
}

// ---------------- launch ----------------

extern "C" void kernel_launch(void* const* d_in, const int* in_sizes, int n_in,
                              void* d_out, int out_size, void* d_ws, size_t ws_size,
                              hipStream_t stream) {
    const float* x    = (const float*)d_in[0];
    const float* w    = (const float*)d_in[1];
    const float* W1   = (const float*)d_in[2];
    const float* fc1W = (const float*)d_in[3];
    const float* gam  = (const float*)d_in[4];
    const float* bet  = (const float*)d_in[5];
    const float* W2   = (const float*)d_in[6];
    const float* W3   = (const float*)d_in[7];
    const int* src = (const int*)d_in[8];
    const int* dst = (const int*)d_in[9];
    const int* gid = (const int*)d_in[10];
    float* out = (float*)d_out;

    float* ws = (float*)d_ws;
    // layout (float-slot offsets); total span ~24.83M floats ~= 99.3 MB
    float* out_inv = ws + 0;                              // 40000
    float* in_inv  = ws + 40000;                          // 40000
    float* ew      = ws + 80000;                          // 320000
    float* ro      = ws + 400000;                         // 8192
    unsigned short* W1t  = (unsigned short*)(ws + 410000);  // 256x128 bf16
    unsigned short* fc1t = (unsigned short*)(ws + 426384);  // 256x128
    unsigned short* W2t  = (unsigned short*)(ws + 442768);  // 256x512
    unsigned short* W3t  = (unsigned short*)(ws + 508304);  // 128x256
    int* cnt_out = (int*)(ws + 524688);                   // 40000
    int* cnt_in  = (int*)(ws + 564688);                   // 40000
    int* cursor  = (int*)(ws + 604688);                   // 40000
    int* off     = (int*)(ws + 644688);                   // 40001
    int* srcs    = (int*)(ws + 684690);                   // 320000
    float* ewp   = ws + 1004690;                          // 320000
    float* ewps  = ws + 1324690;                          // 320000
    unsigned short* xb    = (unsigned short*)(ws + 1650000);  // [M_PAD][128] ; later Q3b
    unsigned short* Q3b   = xb;
    unsigned short* agg1b = (unsigned short*)(ws + 4250000);  // [M_PAD][128] ; later x2b [M_PAD][256]
    unsigned short* x2b   = agg1b;
    unsigned short* x1b   = (unsigned short*)(ws + 9400000);  // [M_PAD][256] ; later x3 fp32 [40000][128]
    float*          x3    = (float*)x1b;
    unsigned short* f1b   = (unsigned short*)(ws + 14550000); // [M_PAD][256]
    unsigned short* P2b   = (unsigned short*)(ws + 19700000); // [M_PAD][256]

    // --- zero histogram/cursor (contiguous) + readout accumulator ---
    hipMemsetAsync(cnt_out, 0, 3 * 40000 * sizeof(int), stream);
    hipMemsetAsync(ro, 0, (size_t)N_GRAPHS * OUT_DIM * sizeof(float), stream);

    // --- weights -> bf16 transposed [N][K] ---
    transpose_cvt<<<(IN_DIM * HID4 + 255) / 256, 256, 0, stream>>>(W1, W1t, IN_DIM, HID4);
    transpose_cvt<<<(IN_DIM * HID4 + 255) / 256, 256, 0, stream>>>(fc1W, fc1t, IN_DIM, HID4);
    transpose_cvt<<<(2 * HID4 * HID4 + 255) / 256, 256, 0, stream>>>(W2, W2t, 2 * HID4, HID4);
    transpose_cvt<<<(HID4 * OUT_DIM + 255) / 256, 256, 0, stream>>>(W3, W3t, HID4, OUT_DIM);

    // --- degrees, edge weights, CSR ---
    edge_prep<<<(N_EDGES + 255) / 256, 256, 0, stream>>>(w, src, dst, ew, cnt_out, cnt_in);
    node_prep<<<(N_NODES + 255) / 256, 256, 0, stream>>>(cnt_out, cnt_in, out_inv, in_inv);
    scan_offsets<<<1, 1024, 0, stream>>>(cnt_in, off);
    csr_fill<<<(N_EDGES + 255) / 256, 256, 0, stream>>>(src, dst, ew, out_inv, off, cursor,
                                                        srcs, ewp, ewps);

    // --- x -> bf16 ---
    cvt_f32_bf16<<<(N_NODES * IN_DIM + 255) / 256, 256, 0, stream>>>(x, xb, N_NODES * IN_DIM);

    // --- conv1: agg1b = in_inv ⊙ gather(ewps * xb[src]); x1b = relu(agg1b @ W1) ---
    gather_nodes<IN_DIM, 0, 1><<<N_NODES, IN_DIM, 0, stream>>>(xb, off, srcs, ewps, in_inv, agg1b);
    {
        dim3 grid(M_PAD / 128, HID4 / 128);
        gemm_mfma<1, 0><<<grid, 256, 0, stream>>>(agg1b, nullptr, W1t, x1b, nullptr,
                                                  IN_DIM, 0, HID4);
    }

    // --- fc1: f1b = LN_relu(xb @ fc1_W) ---
    {
        dim3 grid(M_PAD / 128, HID4 / 128);
        gemm_mfma<0, 0><<<grid, 256, 0, stream>>>(xb, nullptr, fc1t, f1b, nullptr,
                                                  IN_DIM, 0, HID4);
    }
    ln_relu_bf16<<<N_NODES / 4, 256, 0, stream>>>(f1b, gam, bet);

    // --- conv2: P2b = (x1b@W2_top + f1b@W2_bot) ⊙ out_inv ; x2b = relu(in_inv ⊙ gather(ewp * P2b[src])) ---
    {
        dim3 grid(M_PAD / 128, HID4 / 128);
        gemm_mfma<0, 1><<<grid, 256, 0, stream>>>(x1b, f1b, W2t, P2b, out_inv,
                                                  HID4, HID4, HID4);
    }
    gather_nodes<HID4, 1, 1><<<N_NODES, HID4, 0, stream>>>(P2b, off, srcs, ewp, in_inv, x2b);

    // --- conv3: Q3b = (x2b @ W3) ⊙ out_inv ; x3 = relu(in_inv ⊙ gather(ewp * Q3b[src])) ---
    {
        dim3 grid(M_PAD / 128, OUT_DIM / 128);
        gemm_mfma<0, 1><<<grid, 256, 0, stream>>>(x2b, nullptr, W3t, Q3b, out_inv,
                                                  HID4, 0, OUT_DIM);
    }
    gather_nodes<OUT_DIM, 1, 0><<<N_NODES, OUT_DIM, 0, stream>>>(Q3b, off, srcs, ewp, in_inv, x3);

    // --- readout + normalize ---
    readout_sum<<<(N_NODES + NODES_PER_BLOCK - 1) / NODES_PER_BLOCK, 128, 0, stream>>>(x3, gid, ro);
    normalize_out<<<N_GRAPHS, 128, 0, stream>>>(ro, out);
}

// Round 5
// 303.846 us; speedup vs baseline: 3.6562x; 1.5050x over previous
//
#include <hip/hip_runtime.h>

#define N_NODES 40000
#define M_PAD   40064   // 313 * 128
#define N_EDGES 320000
#define N_GRAPHS 64
#define IN_DIM 128
#define HID4 256
#define OUT_DIM 128
#define LN_EPS 1e-5f

typedef short  s16x8  __attribute__((ext_vector_type(8)));
typedef short  s16x4  __attribute__((ext_vector_type(4)));
typedef __bf16 bf16x8 __attribute__((ext_vector_type(8)));
typedef float  f32x4  __attribute__((ext_vector_type(4)));

__device__ __forceinline__ unsigned short f2b(float f) {
    unsigned int u = __builtin_bit_cast(unsigned int, f);
    u += 0x7fffu + ((u >> 16) & 1u);   // round-to-nearest-even
    return (unsigned short)(u >> 16);
}
__device__ __forceinline__ float b2f(unsigned short h) {
    unsigned int u = (unsigned int)h << 16;
    return __builtin_bit_cast(float, u);
}

// ---------------- prep kernels ----------------

__global__ void edge_prep(const float* __restrict__ w, const int* __restrict__ src,
                          const int* __restrict__ dst, float* __restrict__ ew,
                          int* __restrict__ cnt_out, int* __restrict__ cnt_in) {
    int e = blockIdx.x * 256 + threadIdx.x;
    if (e >= N_EDGES) return;
    float4 v = ((const float4*)w)[e];
    ew[e] = fmaxf(fmaxf(v.x, v.y), fmaxf(v.z, v.w));
    atomicAdd(&cnt_out[src[e]], 1);
    atomicAdd(&cnt_in[dst[e]], 1);
}

// stage 1: 40 blocks x 256 threads, block b sums cnt[b*1000 .. b*1000+999]
__global__ void scan_part(const int* __restrict__ cnt, int* __restrict__ partial) {
    int b = blockIdx.x;
    int s = 0;
    for (int i = threadIdx.x; i < 1000; i += 256) s += cnt[b * 1000 + i];
#pragma unroll
    for (int m = 1; m < 64; m <<= 1) s += __shfl_xor(s, m);
    __shared__ int wsm[4];
    if ((threadIdx.x & 63) == 0) wsm[threadIdx.x >> 6] = s;
    __syncthreads();
    if (threadIdx.x == 0) partial[b] = wsm[0] + wsm[1] + wsm[2] + wsm[3];
}

// stage 2: 40 blocks x 1024 threads; exclusive scan -> off ; also node_prep (inv sqrt degs)
__global__ void scan_final(const int* __restrict__ cnt_in, const int* __restrict__ cnt_out,
                           const int* __restrict__ partial, int* __restrict__ off,
                           float* __restrict__ out_inv, float* __restrict__ in_inv) {
    int b = blockIdx.x, tid = threadIdx.x;
    int lane = tid & 63, wv = tid >> 6;
    int pre = 0;
    for (int j = 0; j < b; ++j) pre += partial[j];
    int i = b * 1000 + tid;
    int v = (tid < 1000) ? cnt_in[i] : 0;
    int x = v;
#pragma unroll
    for (int ofs = 1; ofs < 64; ofs <<= 1) {
        int t = __shfl_up(x, ofs);
        if (lane >= ofs) x += t;
    }
    __shared__ int wsum[16];
    if (lane == 63) wsum[wv] = x;
    __syncthreads();
    if (wv == 0 && lane < 16) {
        int s = wsum[lane];
#pragma unroll
        for (int ofs = 1; ofs < 16; ofs <<= 1) {
            int t = __shfl_up(s, ofs);
            if (lane >= ofs) s += t;
        }
        wsum[lane] = s;
    }
    __syncthreads();
    int incl = pre + (wv > 0 ? wsum[wv - 1] : 0) + x;
    if (tid < 1000) {
        off[i] = incl - v;   // exclusive
        in_inv[i] = rsqrtf(fmaxf((float)v, 1.0f));
        out_inv[i] = rsqrtf(fmaxf((float)cnt_out[i], 1.0f));
    }
    if (b == 39 && tid == 999) off[N_NODES] = incl;
}

// consumes cnt_in as a countdown cursor (dead after scan_final)
__global__ void csr_fill(const int* __restrict__ src, const int* __restrict__ dst,
                         const float* __restrict__ ew, const float* __restrict__ out_inv,
                         const int* __restrict__ off, int* __restrict__ cnt_in,
                         int* __restrict__ srcs, float* __restrict__ ewp,
                         float* __restrict__ ewps) {
    int e = blockIdx.x * 256 + threadIdx.x;
    if (e >= N_EDGES) return;
    int d = dst[e];
    int slot = off[d] + atomicSub(&cnt_in[d], 1) - 1;
    int s = src[e];
    float wv = ew[e];
    srcs[slot] = s;
    ewp[slot] = wv;
    ewps[slot] = wv * out_inv[s];
}

// ---------------- fused conversions: x -> bf16 ; 4 weights -> bf16 transposed [N][K] ----------------

#define XN (N_NODES * IN_DIM)   // 5,120,000

__global__ void cvt_all(const float* __restrict__ x, const float* __restrict__ W1,
                        const float* __restrict__ fc1, const float* __restrict__ W2,
                        const float* __restrict__ W3, unsigned short* __restrict__ xb,
                        unsigned short* __restrict__ W1t, unsigned short* __restrict__ fc1t,
                        unsigned short* __restrict__ W2t, unsigned short* __restrict__ W3t) {
    int idx = blockIdx.x * 256 + threadIdx.x;
    if (idx < XN) { xb[idx] = f2b(x[idx]); return; }
    int j = idx - XN;
    if (j < 32768) { int k = j >> 8, n = j & 255; W1t[n * 128 + k] = f2b(W1[j]); return; }
    j -= 32768;
    if (j < 32768) { int k = j >> 8, n = j & 255; fc1t[n * 128 + k] = f2b(fc1[j]); return; }
    j -= 32768;
    if (j < 131072) { int k = j >> 8, n = j & 255; W2t[n * 512 + k] = f2b(W2[j]); return; }
    j -= 131072;
    if (j < 32768) { int k = j >> 7, n = j & 127; W3t[n * 256 + k] = f2b(W3[j]); }
}

// ---------------- gather aggregation (block per dst node), 2 bf16 per thread ----------------

template <int D, int RELU, int OUT_BF16>
__global__ void gather_nodes(const unsigned short* __restrict__ h, const int* __restrict__ off,
                             const int* __restrict__ srcs, const float* __restrict__ ews,
                             const float* __restrict__ scale, void* __restrict__ outp) {
    int n = blockIdx.x;
    int t = threadIdx.x;  // D/2 threads
    int b = off[n], e = off[n + 1];
    const unsigned int* hu = (const unsigned int*)h;
    float a0 = 0.0f, a1 = 0.0f;
    int i = b;
    for (; i + 1 < e; i += 2) {
        unsigned int p0 = hu[(size_t)srcs[i] * (D / 2) + t];
        unsigned int p1 = hu[(size_t)srcs[i + 1] * (D / 2) + t];
        float w0 = ews[i], w1 = ews[i + 1];
        a0 += w0 * b2f((unsigned short)p0) + w1 * b2f((unsigned short)p1);
        a1 += w0 * b2f((unsigned short)(p0 >> 16)) + w1 * b2f((unsigned short)(p1 >> 16));
    }
    if (i < e) {
        unsigned int p = hu[(size_t)srcs[i] * (D / 2) + t];
        float w0 = ews[i];
        a0 += w0 * b2f((unsigned short)p);
        a1 += w0 * b2f((unsigned short)(p >> 16));
    }
    float sc = scale[n];
    a0 *= sc; a1 *= sc;
    if (RELU) { a0 = fmaxf(a0, 0.0f); a1 = fmaxf(a1, 0.0f); }
    if (OUT_BF16) {
        unsigned int o = (unsigned int)f2b(a0) | ((unsigned int)f2b(a1) << 16);
        ((unsigned int*)outp)[(size_t)n * (D / 2) + t] = o;
    } else {
        ((float2*)outp)[(size_t)n * (D / 2) + t] = make_float2(a0, a1);
    }
}

// ---------------- MFMA bf16 GEMM ----------------
// C[M_PAD][N] (bf16) = epilogue( [A | A2] @ Bt^T ), Bt:[N][K] bf16. 128x128 tile, BK=32.

template <int RELU, int SCALE_C>
__global__ __launch_bounds__(256) void gemm_mfma(
    const unsigned short* __restrict__ A, const unsigned short* __restrict__ A2,
    const unsigned short* __restrict__ Bt, unsigned short* __restrict__ C,
    const float* __restrict__ rowScaleC, int K1, int K2, int N) {
    __shared__ short As[128][40];
    __shared__ short Bs[128][40];
    const int K = K1 + K2;
    int tid = threadIdx.x;
    int lane = tid & 63, wave = tid >> 6;
    int wm = (wave >> 1) * 64, wn = (wave & 1) * 64;
    int quad = lane >> 4, r16 = lane & 15;
    int m0 = blockIdx.x * 128, n0 = blockIdx.y * 128;

    f32x4 acc[4][4] = {};

    int ra = tid >> 2;
    int ca = (tid & 3) * 8;

    for (int k0 = 0; k0 < K; k0 += 32) {
#pragma unroll
        for (int h = 0; h < 2; ++h) {
            int r = ra + h * 64;
            int kk = k0 + ca;
            const unsigned short* Ap = (kk < K1)
                ? A  + (size_t)(m0 + r) * K1 + kk
                : A2 + (size_t)(m0 + r) * K2 + (kk - K1);
            *(s16x8*)&As[r][ca] = *(const s16x8*)Ap;
            *(s16x8*)&Bs[r][ca] = *(const s16x8*)(Bt + (size_t)(n0 + r) * K + kk);
        }
        __syncthreads();
        s16x8 af[4], bfr[4];
#pragma unroll
        for (int i = 0; i < 4; ++i) af[i]  = *(const s16x8*)&As[wm + i * 16 + r16][quad * 8];
#pragma unroll
        for (int j = 0; j < 4; ++j) bfr[j] = *(const s16x8*)&Bs[wn + j * 16 + r16][quad * 8];
#pragma unroll
        for (int i = 0; i < 4; ++i)
#pragma unroll
            for (int j = 0; j < 4; ++j)
                acc[i][j] = __builtin_amdgcn_mfma_f32_16x16x32_bf16(
                    __builtin_bit_cast(bf16x8, af[i]), __builtin_bit_cast(bf16x8, bfr[j]),
                    acc[i][j], 0, 0, 0);
        __syncthreads();
    }

#pragma unroll
    for (int i = 0; i < 4; ++i) {
        int mbase = m0 + wm + i * 16 + quad * 4;
#pragma unroll
        for (int r = 0; r < 4; ++r) {
            int m = mbase + r;
            float sc = SCALE_C ? rowScaleC[m] : 1.0f;
#pragma unroll
            for (int j = 0; j < 4; ++j) {
                float v = acc[i][j][r] * sc;
                if (RELU) v = fmaxf(v, 0.0f);
                C[(size_t)m * N + n0 + wn + j * 16 + r16] = f2b(v);
            }
        }
    }
}

// ---------------- LayerNorm + ReLU, in-place bf16 (wave per row, 256 cols) ----------------

__global__ void ln_relu_bf16(unsigned short* __restrict__ f, const float* __restrict__ gamma,
                             const float* __restrict__ beta) {
    int row = (blockIdx.x * 256 + threadIdx.x) >> 6;
    int lane = threadIdx.x & 63;
    if (row >= N_NODES) return;
    s16x4* fr = (s16x4*)(f + (size_t)row * HID4);
    s16x4 pv = fr[lane];
    float v0 = b2f((unsigned short)pv[0]);
    float v1 = b2f((unsigned short)pv[1]);
    float v2 = b2f((unsigned short)pv[2]);
    float v3 = b2f((unsigned short)pv[3]);
    float sum = v0 + v1 + v2 + v3;
#pragma unroll
    for (int m = 1; m < 64; m <<= 1) sum += __shfl_xor(sum, m);
    float mu = sum * (1.0f / HID4);
    float d0 = v0 - mu, d1 = v1 - mu, d2 = v2 - mu, d3 = v3 - mu;
    float sq = d0 * d0 + d1 * d1 + d2 * d2 + d3 * d3;
#pragma unroll
    for (int m = 1; m < 64; m <<= 1) sq += __shfl_xor(sq, m);
    float rs = rsqrtf(sq * (1.0f / HID4) + LN_EPS);
    int c = lane * 4;
    s16x4 ov;
    ov[0] = (short)f2b(fmaxf(d0 * rs * gamma[c + 0] + beta[c + 0], 0.0f));
    ov[1] = (short)f2b(fmaxf(d1 * rs * gamma[c + 1] + beta[c + 1], 0.0f));
    ov[2] = (short)f2b(fmaxf(d2 * rs * gamma[c + 2] + beta[c + 2], 0.0f));
    ov[3] = (short)f2b(fmaxf(d3 * rs * gamma[c + 3] + beta[c + 3], 0.0f));
    fr[lane] = ov;
}

// ---------------- readout (parallel: 16 nodes/block) ----------------

#define RO_NPB 16

__global__ void readout_sum(const float* __restrict__ x3, const int* __restrict__ gid,
                            float* __restrict__ ro) {
    int d = threadIdx.x;  // 0..127
    int n0 = blockIdx.x * RO_NPB;
    int n1 = n0 + RO_NPB;
    if (n1 > N_NODES) n1 = N_NODES;
    float acc = 0.0f;
    int cur = gid[n0];
    for (int n = n0; n < n1; ++n) {
        int g = gid[n];
        if (g != cur) {
            atomicAdd(&ro[cur * OUT_DIM + d], acc);
            acc = 0.0f;
            cur = g;
        }
        acc += x3[(size_t)n * OUT_DIM + d];
    }
    atomicAdd(&ro[cur * OUT_DIM + d], acc);
}

__global__ void normalize_out(const float* __restrict__ ro, float* __restrict__ out) {
    int g = blockIdx.x;
    int d = threadIdx.x;  // 128 threads = 2 waves
    float v = ro[g * OUT_DIM + d];
    float ss = v * v;
#pragma unroll
    for (int m = 1; m < 64; m <<= 1) ss += __shfl_xor(ss, m);
    __shared__ float s2[2];
    if ((d & 63) == 0) s2[d >> 6] = ss;
    __syncthreads();
    float tot = s2[0] + s2[1];
    float norm = fmaxf(sqrtf(tot), 1e-12f);
    out[g * OUT_DIM + d] = v / norm;
}

// ---------------- launch ----------------

extern "C" void kernel_launch(void* const* d_in, const int* in_sizes, int n_in,
                              void* d_out, int out_size, void* d_ws, size_t ws_size,
                              hipStream_t stream) {
    const float* x    = (const float*)d_in[0];
    const float* w    = (const float*)d_in[1];
    const float* W1   = (const float*)d_in[2];
    const float* fc1W = (const float*)d_in[3];
    const float* gam  = (const float*)d_in[4];
    const float* bet  = (const float*)d_in[5];
    const float* W2   = (const float*)d_in[6];
    const float* W3   = (const float*)d_in[7];
    const int* src = (const int*)d_in[8];
    const int* dst = (const int*)d_in[9];
    const int* gid = (const int*)d_in[10];
    float* out = (float*)d_out;

    float* ws = (float*)d_ws;
    float* out_inv = ws + 0;                              // 40000
    float* in_inv  = ws + 40000;                          // 40000
    float* ew      = ws + 80000;                          // 320000
    float* ro      = ws + 400000;                         // 8192
    unsigned short* W1t  = (unsigned short*)(ws + 410000);  // [256][128] bf16
    unsigned short* fc1t = (unsigned short*)(ws + 426384);  // [256][128]
    unsigned short* W2t  = (unsigned short*)(ws + 442768);  // [256][512]
    unsigned short* W3t  = (unsigned short*)(ws + 508304);  // [128][256]
    int* cnt_out = (int*)(ws + 524688);                   // 40000
    int* cnt_in  = (int*)(ws + 564688);                   // 40000 (becomes cursor)
    int* partial = (int*)(ws + 604688);                   // 40
    int* off     = (int*)(ws + 604728);                   // 40001
    int* srcs    = (int*)(ws + 644730);                   // 320000
    float* ewp   = ws + 964730;                           // 320000
    float* ewps  = ws + 1284730;                          // 320000
    unsigned short* xb    = (unsigned short*)(ws + 1650000);  // [M_PAD][128] ; later Q3b
    unsigned short* Q3b   = xb;
    unsigned short* agg1b = (unsigned short*)(ws + 4250000);  // [M_PAD][128] ; later x2b [M_PAD][256]
    unsigned short* x2b   = agg1b;
    unsigned short* x1b   = (unsigned short*)(ws + 9400000);  // [M_PAD][256] ; later x3 fp32
    float*          x3    = (float*)x1b;
    unsigned short* f1b   = (unsigned short*)(ws + 14550000); // [M_PAD][256]
    unsigned short* P2b   = (unsigned short*)(ws + 19700000); // [M_PAD][256]

    hipMemsetAsync(cnt_out, 0, 2 * 40000 * sizeof(int), stream);
    hipMemsetAsync(ro, 0, (size_t)N_GRAPHS * OUT_DIM * sizeof(float), stream);

    // conversions (x + all weights, one kernel)
    cvt_all<<<(XN + 229376 + 255) / 256, 256, 0, stream>>>(x, W1, fc1W, W2, W3,
                                                           xb, W1t, fc1t, W2t, W3t);

    // degrees, edge weights, CSR
    edge_prep<<<(N_EDGES + 255) / 256, 256, 0, stream>>>(w, src, dst, ew, cnt_out, cnt_in);
    scan_part<<<40, 256, 0, stream>>>(cnt_in, partial);
    scan_final<<<40, 1024, 0, stream>>>(cnt_in, cnt_out, partial, off, out_inv, in_inv);
    csr_fill<<<(N_EDGES + 255) / 256, 256, 0, stream>>>(src, dst, ew, out_inv, off, cnt_in,
                                                        srcs, ewp, ewps);

    // conv1
    gather_nodes<IN_DIM, 0, 1><<<N_NODES, IN_DIM / 2, 0, stream>>>(xb, off, srcs, ewps, in_inv, agg1b);
    {
        dim3 grid(M_PAD / 128, HID4 / 128);
        gemm_mfma<1, 0><<<grid, 256, 0, stream>>>(agg1b, nullptr, W1t, x1b, nullptr,
                                                  IN_DIM, 0, HID4);
    }

    // fc1
    {
        dim3 grid(M_PAD / 128, HID4 / 128);
        gemm_mfma<0, 0><<<grid, 256, 0, stream>>>(xb, nullptr, fc1t, f1b, nullptr,
                                                  IN_DIM, 0, HID4);
    }
    ln_relu_bf16<<<N_NODES / 4, 256, 0, stream>>>(f1b, gam, bet);

    // conv2
    {
        dim3 grid(M_PAD / 128, HID4 / 128);
        gemm_mfma<0, 1><<<grid, 256, 0, stream>>>(x1b, f1b, W2t, P2b, out_inv,
                                                  HID4, HID4, HID4);
    }
    gather_nodes<HID4, 1, 1><<<N_NODES, HID4 / 2, 0, stream>>>(P2b, off, srcs, ewp, in_inv, x2b);

    // conv3
    {
        dim3 grid(M_PAD / 128, OUT_DIM / 128);
        gemm_mfma<0, 1><<<grid, 256, 0, stream>>>(x2b, nullptr, W3t, Q3b, out_inv,
                                                  HID4, 0, OUT_DIM);
    }
    gather_nodes<OUT_DIM, 1, 0><<<N_NODES, OUT_DIM / 2, 0, stream>>>(Q3b, off, srcs, ewp, in_inv, x3);

    // readout + normalize
    readout_sum<<<(N_NODES + RO_NPB - 1) / RO_NPB, 128, 0, stream>>>(x3, gid, ro);
    normalize_out<<<N_GRAPHS, 128, 0, stream>>>(ro, out);
}

// Round 7
// 298.440 us; speedup vs baseline: 3.7224x; 1.0181x over previous
//
#include <hip/hip_runtime.h>

#define N_NODES 40000
#define M_PAD   40064   // 313 * 128
#define N_EDGES 320000
#define N_GRAPHS 64
#define IN_DIM 128
#define HID4 256
#define OUT_DIM 128
#define LN_EPS 1e-5f

typedef short  s16x8  __attribute__((ext_vector_type(8)));
typedef short  s16x4  __attribute__((ext_vector_type(4)));
typedef __bf16 bf16x8 __attribute__((ext_vector_type(8)));
typedef float  f32x4  __attribute__((ext_vector_type(4)));

__device__ __forceinline__ unsigned short f2b(float f) {
    unsigned int u = __builtin_bit_cast(unsigned int, f);
    u += 0x7fffu + ((u >> 16) & 1u);   // round-to-nearest-even
    return (unsigned short)(u >> 16);
}
__device__ __forceinline__ float b2f(unsigned short h) {
    unsigned int u = (unsigned int)h << 16;
    return __builtin_bit_cast(float, u);
}

// ---------------- fused prep: x->bf16, weights->bf16 transposed, edge ew + degree histograms ----

#define XN (N_NODES * IN_DIM)          // 5,120,000
#define WN 229376                      // 32768*3 + 131072
#define PREP_TOT (XN + WN + N_EDGES)

__global__ void prep_all(const float* __restrict__ x, const float* __restrict__ W1,
                         const float* __restrict__ fc1, const float* __restrict__ W2,
                         const float* __restrict__ W3, const float* __restrict__ w,
                         const int* __restrict__ src, const int* __restrict__ dst,
                         unsigned short* __restrict__ xb, unsigned short* __restrict__ W1t,
                         unsigned short* __restrict__ fc1t, unsigned short* __restrict__ W2t,
                         unsigned short* __restrict__ W3t, float* __restrict__ ew,
                         int* __restrict__ cnt_out, int* __restrict__ cnt_in) {
    int idx = blockIdx.x * 256 + threadIdx.x;
    if (idx < XN) { xb[idx] = f2b(x[idx]); return; }
    int j = idx - XN;
    if (j < 32768) { int k = j >> 8, n = j & 255; W1t[n * 128 + k] = f2b(W1[j]); return; }
    j -= 32768;
    if (j < 32768) { int k = j >> 8, n = j & 255; fc1t[n * 128 + k] = f2b(fc1[j]); return; }
    j -= 32768;
    if (j < 131072) { int k = j >> 8, n = j & 255; W2t[n * 512 + k] = f2b(W2[j]); return; }
    j -= 131072;
    if (j < 32768) { int k = j >> 7, n = j & 127; W3t[n * 256 + k] = f2b(W3[j]); return; }
    j -= 32768;
    if (j < N_EDGES) {
        float4 v = ((const float4*)w)[j];
        ew[j] = fmaxf(fmaxf(v.x, v.y), fmaxf(v.z, v.w));
        atomicAdd(&cnt_out[src[j]], 1);
        atomicAdd(&cnt_in[dst[j]], 1);
    }
}

// stage 1: 40 blocks x 256 threads, block b sums cnt[b*1000 .. b*1000+999]
__global__ void scan_part(const int* __restrict__ cnt, int* __restrict__ partial) {
    int b = blockIdx.x;
    int s = 0;
    for (int i = threadIdx.x; i < 1000; i += 256) s += cnt[b * 1000 + i];
#pragma unroll
    for (int m = 1; m < 64; m <<= 1) s += __shfl_xor(s, m);
    __shared__ int wsm[4];
    if ((threadIdx.x & 63) == 0) wsm[threadIdx.x >> 6] = s;
    __syncthreads();
    if (threadIdx.x == 0) partial[b] = wsm[0] + wsm[1] + wsm[2] + wsm[3];
}

// stage 2: 40 blocks x 1024 threads; exclusive scan -> off ; also inv-sqrt degrees
__global__ void scan_final(const int* __restrict__ cnt_in, const int* __restrict__ cnt_out,
                           const int* __restrict__ partial, int* __restrict__ off,
                           float* __restrict__ out_inv, float* __restrict__ in_inv) {
    int b = blockIdx.x, tid = threadIdx.x;
    int lane = tid & 63, wv = tid >> 6;
    int pre = 0;
    for (int j = 0; j < b; ++j) pre += partial[j];
    int i = b * 1000 + tid;
    int v = (tid < 1000) ? cnt_in[i] : 0;
    int x = v;
#pragma unroll
    for (int ofs = 1; ofs < 64; ofs <<= 1) {
        int t = __shfl_up(x, ofs);
        if (lane >= ofs) x += t;
    }
    __shared__ int wsum[16];
    if (lane == 63) wsum[wv] = x;
    __syncthreads();
    if (wv == 0 && lane < 16) {
        int s = wsum[lane];
#pragma unroll
        for (int ofs = 1; ofs < 16; ofs <<= 1) {
            int t = __shfl_up(s, ofs);
            if (lane >= ofs) s += t;
        }
        wsum[lane] = s;
    }
    __syncthreads();
    int incl = pre + (wv > 0 ? wsum[wv - 1] : 0) + x;
    if (tid < 1000) {
        off[i] = incl - v;   // exclusive
        in_inv[i] = rsqrtf(fmaxf((float)v, 1.0f));
        out_inv[i] = rsqrtf(fmaxf((float)cnt_out[i], 1.0f));
    }
    if (b == 39 && tid == 999) off[N_NODES] = incl;
}

// consumes cnt_in as countdown cursor; emits packed (src, weight) records
__global__ void csr_fill(const int* __restrict__ src, const int* __restrict__ dst,
                         const float* __restrict__ ew, const float* __restrict__ out_inv,
                         const int* __restrict__ off, int* __restrict__ cnt_in,
                         int2* __restrict__ es1, int2* __restrict__ es23) {
    int e = blockIdx.x * 256 + threadIdx.x;
    if (e >= N_EDGES) return;
    int d = dst[e];
    int slot = off[d] + atomicSub(&cnt_in[d], 1) - 1;
    int s = src[e];
    float wv = ew[e];
    es1[slot] = make_int2(s, __float_as_int(wv * out_inv[s]));
    es23[slot] = make_int2(s, __float_as_int(wv));
}

// ---------------- gather aggregation (block per dst node), packed edges ----------------

template <int D, int RELU>
__global__ void gather_nodes(const unsigned short* __restrict__ h, const int* __restrict__ off,
                             const int2* __restrict__ eg, const float* __restrict__ scale,
                             unsigned short* __restrict__ outb) {
    int n = blockIdx.x;
    int t = threadIdx.x;  // D/2 threads
    int b = off[n], e = off[n + 1];
    const unsigned int* hu = (const unsigned int*)h;
    float a0 = 0.0f, a1 = 0.0f;
    int i = b;
    for (; i + 3 < e; i += 4) {
        int2 e0 = eg[i], e1 = eg[i + 1], e2 = eg[i + 2], e3 = eg[i + 3];
        unsigned int p0 = hu[(size_t)e0.x * (D / 2) + t];
        unsigned int p1 = hu[(size_t)e1.x * (D / 2) + t];
        unsigned int p2 = hu[(size_t)e2.x * (D / 2) + t];
        unsigned int p3 = hu[(size_t)e3.x * (D / 2) + t];
        float w0 = __int_as_float(e0.y), w1 = __int_as_float(e1.y);
        float w2 = __int_as_float(e2.y), w3 = __int_as_float(e3.y);
        a0 += w0 * b2f((unsigned short)p0) + w1 * b2f((unsigned short)p1)
            + w2 * b2f((unsigned short)p2) + w3 * b2f((unsigned short)p3);
        a1 += w0 * b2f((unsigned short)(p0 >> 16)) + w1 * b2f((unsigned short)(p1 >> 16))
            + w2 * b2f((unsigned short)(p2 >> 16)) + w3 * b2f((unsigned short)(p3 >> 16));
    }
    for (; i < e; ++i) {
        int2 ee = eg[i];
        unsigned int p = hu[(size_t)ee.x * (D / 2) + t];
        float w0 = __int_as_float(ee.y);
        a0 += w0 * b2f((unsigned short)p);
        a1 += w0 * b2f((unsigned short)(p >> 16));
    }
    float sc = scale[n];
    a0 *= sc; a1 *= sc;
    if (RELU) { a0 = fmaxf(a0, 0.0f); a1 = fmaxf(a1, 0.0f); }
    unsigned int o = (unsigned int)f2b(a0) | ((unsigned int)f2b(a1) << 16);
    ((unsigned int*)outb)[(size_t)n * (D / 2) + t] = o;
}

// ---------------- MFMA bf16 GEMM (generic, 128x128 tile, BK=32) ----------------

template <int RELU, int SCALE_C>
__global__ __launch_bounds__(256) void gemm_mfma(
    const unsigned short* __restrict__ A, const unsigned short* __restrict__ A2,
    const unsigned short* __restrict__ Bt, unsigned short* __restrict__ C,
    const float* __restrict__ rowScaleC, int K1, int K2, int N) {
    __shared__ short As[128][40];
    __shared__ short Bs[128][40];
    const int K = K1 + K2;
    int tid = threadIdx.x;
    int lane = tid & 63, wave = tid >> 6;
    int wm = (wave >> 1) * 64, wn = (wave & 1) * 64;
    int quad = lane >> 4, r16 = lane & 15;
    int m0 = blockIdx.x * 128, n0 = blockIdx.y * 128;

    f32x4 acc[4][4] = {};
    int ra = tid >> 2;
    int ca = (tid & 3) * 8;

    for (int k0 = 0; k0 < K; k0 += 32) {
#pragma unroll
        for (int h = 0; h < 2; ++h) {
            int r = ra + h * 64;
            int kk = k0 + ca;
            const unsigned short* Ap = (kk < K1)
                ? A  + (size_t)(m0 + r) * K1 + kk
                : A2 + (size_t)(m0 + r) * K2 + (kk - K1);
            *(s16x8*)&As[r][ca] = *(const s16x8*)Ap;
            *(s16x8*)&Bs[r][ca] = *(const s16x8*)(Bt + (size_t)(n0 + r) * K + kk);
        }
        __syncthreads();
        s16x8 af[4], bfr[4];
#pragma unroll
        for (int i = 0; i < 4; ++i) af[i]  = *(const s16x8*)&As[wm + i * 16 + r16][quad * 8];
#pragma unroll
        for (int j = 0; j < 4; ++j) bfr[j] = *(const s16x8*)&Bs[wn + j * 16 + r16][quad * 8];
#pragma unroll
        for (int i = 0; i < 4; ++i)
#pragma unroll
            for (int j = 0; j < 4; ++j)
                acc[i][j] = __builtin_amdgcn_mfma_f32_16x16x32_bf16(
                    __builtin_bit_cast(bf16x8, af[i]), __builtin_bit_cast(bf16x8, bfr[j]),
                    acc[i][j], 0, 0, 0);
        __syncthreads();
    }

#pragma unroll
    for (int i = 0; i < 4; ++i) {
        int mbase = m0 + wm + i * 16 + quad * 4;
#pragma unroll
        for (int r = 0; r < 4; ++r) {
            int m = mbase + r;
            float sc = SCALE_C ? rowScaleC[m] : 1.0f;
#pragma unroll
            for (int j = 0; j < 4; ++j) {
                float v = acc[i][j][r] * sc;
                if (RELU) v = fmaxf(v, 0.0f);
                C[(size_t)m * N + n0 + wn + j * 16 + r16] = f2b(v);
            }
        }
    }
}

// ---------------- dual GEMM: conv1 (z=0, relu) + fc1 (z=1) ; K=128, N=256 ----------------

__global__ __launch_bounds__(256) void gemm_dual(
    const unsigned short* __restrict__ A0, const unsigned short* __restrict__ B0,
    unsigned short* __restrict__ C0,
    const unsigned short* __restrict__ A1, const unsigned short* __restrict__ B1,
    unsigned short* __restrict__ C1) {
    const unsigned short* A  = blockIdx.z ? A1 : A0;
    const unsigned short* Bt = blockIdx.z ? B1 : B0;
    unsigned short* C        = blockIdx.z ? C1 : C0;
    const int relu = (blockIdx.z == 0);
    __shared__ short As[128][40];
    __shared__ short Bs[128][40];
    int tid = threadIdx.x;
    int lane = tid & 63, wave = tid >> 6;
    int wm = (wave >> 1) * 64, wn = (wave & 1) * 64;
    int quad = lane >> 4, r16 = lane & 15;
    int m0 = blockIdx.x * 128, n0 = blockIdx.y * 128;

    f32x4 acc[4][4] = {};
    int ra = tid >> 2;
    int ca = (tid & 3) * 8;

    for (int k0 = 0; k0 < 128; k0 += 32) {
#pragma unroll
        for (int h = 0; h < 2; ++h) {
            int r = ra + h * 64;
            int kk = k0 + ca;
            *(s16x8*)&As[r][ca] = *(const s16x8*)(A + (size_t)(m0 + r) * 128 + kk);
            *(s16x8*)&Bs[r][ca] = *(const s16x8*)(Bt + (size_t)(n0 + r) * 128 + kk);
        }
        __syncthreads();
        s16x8 af[4], bfr[4];
#pragma unroll
        for (int i = 0; i < 4; ++i) af[i]  = *(const s16x8*)&As[wm + i * 16 + r16][quad * 8];
#pragma unroll
        for (int j = 0; j < 4; ++j) bfr[j] = *(const s16x8*)&Bs[wn + j * 16 + r16][quad * 8];
#pragma unroll
        for (int i = 0; i < 4; ++i)
#pragma unroll
            for (int j = 0; j < 4; ++j)
                acc[i][j] = __builtin_amdgcn_mfma_f32_16x16x32_bf16(
                    __builtin_bit_cast(bf16x8, af[i]), __builtin_bit_cast(bf16x8, bfr[j]),
                    acc[i][j], 0, 0, 0);
        __syncthreads();
    }

#pragma unroll
    for (int i = 0; i < 4; ++i) {
        int mbase = m0 + wm + i * 16 + quad * 4;
#pragma unroll
        for (int r = 0; r < 4; ++r) {
            int m = mbase + r;
#pragma unroll
            for (int j = 0; j < 4; ++j) {
                float v = acc[i][j][r];
                if (relu) v = fmaxf(v, 0.0f);
                C[(size_t)m * 256 + n0 + wn + j * 16 + r16] = f2b(v);
            }
        }
    }
}

// ---------------- LayerNorm + ReLU, in-place bf16 (wave per row, 256 cols) ----------------

__global__ void ln_relu_bf16(unsigned short* __restrict__ f, const float* __restrict__ gamma,
                             const float* __restrict__ beta) {
    int row = (blockIdx.x * 256 + threadIdx.x) >> 6;
    int lane = threadIdx.x & 63;
    if (row >= N_NODES) return;
    s16x4* fr = (s16x4*)(f + (size_t)row * HID4);
    s16x4 pv = fr[lane];
    float v0 = b2f((unsigned short)pv[0]);
    float v1 = b2f((unsigned short)pv[1]);
    float v2 = b2f((unsigned short)pv[2]);
    float v3 = b2f((unsigned short)pv[3]);
    float sum = v0 + v1 + v2 + v3;
#pragma unroll
    for (int m = 1; m < 64; m <<= 1) sum += __shfl_xor(sum, m);
    float mu = sum * (1.0f / HID4);
    float d0 = v0 - mu, d1 = v1 - mu, d2 = v2 - mu, d3 = v3 - mu;
    float sq = d0 * d0 + d1 * d1 + d2 * d2 + d3 * d3;
#pragma unroll
    for (int m = 1; m < 64; m <<= 1) sq += __shfl_xor(sq, m);
    float rs = rsqrtf(sq * (1.0f / HID4) + LN_EPS);
    int c = lane * 4;
    s16x4 ov;
    ov[0] = (short)f2b(fmaxf(d0 * rs * gamma[c + 0] + beta[c + 0], 0.0f));
    ov[1] = (short)f2b(fmaxf(d1 * rs * gamma[c + 1] + beta[c + 1], 0.0f));
    ov[2] = (short)f2b(fmaxf(d2 * rs * gamma[c + 2] + beta[c + 2], 0.0f));
    ov[3] = (short)f2b(fmaxf(d3 * rs * gamma[c + 3] + beta[c + 3], 0.0f));
    fr[lane] = ov;
}

// ---------------- readout (16 nodes/block, bf16 in) ----------------

#define RO_NPB 16

__global__ void readout_sum(const unsigned short* __restrict__ x3, const int* __restrict__ gid,
                            float* __restrict__ ro) {
    int d = threadIdx.x;  // 0..127
    int n0 = blockIdx.x * RO_NPB;
    int n1 = n0 + RO_NPB;
    if (n1 > N_NODES) n1 = N_NODES;
    float acc = 0.0f;
    int cur = gid[n0];
    for (int n = n0; n < n1; ++n) {
        int g = gid[n];
        if (g != cur) {
            atomicAdd(&ro[cur * OUT_DIM + d], acc);
            acc = 0.0f;
            cur = g;
        }
        acc += b2f(x3[(size_t)n * OUT_DIM + d]);
    }
    atomicAdd(&ro[cur * OUT_DIM + d], acc);
}

__global__ void normalize_out(const float* __restrict__ ro, float* __restrict__ out) {
    int g = blockIdx.x;
    int d = threadIdx.x;  // 128 threads = 2 waves
    float v = ro[g * OUT_DIM + d];
    float ss = v * v;
#pragma unroll
    for (int m = 1; m < 64; m <<= 1) ss += __shfl_xor(ss, m);
    __shared__ float s2[2];
    if ((d & 63) == 0) s2[d >> 6] = ss;
    __syncthreads();
    float tot = s2[0] + s2[1];
    float norm = fmaxf(sqrtf(tot), 1e-12f);
    out[g * OUT_DIM + d] = v / norm;
}

// ---------------- launch ----------------

extern "C" void kernel_launch(void* const* d_in, const int* in_sizes, int n_in,
                              void* d_out, int out_size, void* d_ws, size_t ws_size,
                              hipStream_t stream) {
    const float* x    = (const float*)d_in[0];
    const float* w    = (const float*)d_in[1];
    const float* W1   = (const float*)d_in[2];
    const float* fc1W = (const float*)d_in[3];
    const float* gam  = (const float*)d_in[4];
    const float* bet  = (const float*)d_in[5];
    const float* W2   = (const float*)d_in[6];
    const float* W3   = (const float*)d_in[7];
    const int* src = (const int*)d_in[8];
    const int* dst = (const int*)d_in[9];
    const int* gid = (const int*)d_in[10];
    float* out = (float*)d_out;

    float* ws = (float*)d_ws;
    float* out_inv = ws + 0;                                 // 40000
    float* in_inv  = ws + 40000;                             // 40000
    float* ew      = ws + 80000;                             // 320000
    int*   cnt_out = (int*)(ws + 400000);                    // 40000 (memset group start)
    int*   cnt_in  = (int*)(ws + 440000);                    // 40000 (memset group)
    float* ro      = ws + 480000;                            // 8192 (memset group end)
    unsigned short* W1t  = (unsigned short*)(ws + 488192);   // [256][128]
    unsigned short* fc1t = (unsigned short*)(ws + 504576);   // [256][128]
    unsigned short* W2t  = (unsigned short*)(ws + 520960);   // [256][512]
    unsigned short* W3t  = (unsigned short*)(ws + 586496);   // [128][256]
    int*   partial = (int*)(ws + 602880);                    // 40
    int*   off     = (int*)(ws + 602920);                    // 40001
    int2*  es1     = (int2*)(ws + 642922);                   // 320000 int2
    int2*  es23    = (int2*)(ws + 1282922);                  // 320000 int2
    unsigned short* xb    = (unsigned short*)(ws + 1923000); // [M_PAD][128] ; later Q3b
    unsigned short* Q3b   = xb;
    unsigned short* agg1b = (unsigned short*)(ws + 4487100); // [M_PAD][128..256] ; later x2b
    unsigned short* x2b   = agg1b;
    unsigned short* x1b   = (unsigned short*)(ws + 9615300); // [M_PAD][256] ; later x3 bf16
    unsigned short* x3b   = x1b;
    unsigned short* f1b   = (unsigned short*)(ws + 14743500);// [M_PAD][256]
    unsigned short* P2b   = (unsigned short*)(ws + 19871700);// [M_PAD][256]

    // one memset covers cnt_out | cnt_in | ro (contiguous)
    hipMemsetAsync(cnt_out, 0, (2 * 40000 + N_GRAPHS * OUT_DIM) * sizeof(float), stream);

    // fused conversions + edge weights + degree histograms
    prep_all<<<(PREP_TOT + 255) / 256, 256, 0, stream>>>(x, W1, fc1W, W2, W3, w, src, dst,
                                                         xb, W1t, fc1t, W2t, W3t, ew,
                                                         cnt_out, cnt_in);
    scan_part<<<40, 256, 0, stream>>>(cnt_in, partial);
    scan_final<<<40, 1024, 0, stream>>>(cnt_in, cnt_out, partial, off, out_inv, in_inv);
    csr_fill<<<(N_EDGES + 255) / 256, 256, 0, stream>>>(src, dst, ew, out_inv, off, cnt_in,
                                                        es1, es23);

    // conv1 gather, then fused conv1+fc1 GEMM
    gather_nodes<IN_DIM, 0><<<N_NODES, IN_DIM / 2, 0, stream>>>(xb, off, es1, in_inv, agg1b);
    {
        dim3 grid(M_PAD / 128, HID4 / 128, 2);
        gemm_dual<<<grid, 256, 0, stream>>>(agg1b, W1t, x1b, xb, fc1t, f1b);
    }
    ln_relu_bf16<<<N_NODES / 4, 256, 0, stream>>>(f1b, gam, bet);

    // conv2
    {
        dim3 grid(M_PAD / 128, HID4 / 128);
        gemm_mfma<0, 1><<<grid, 256, 0, stream>>>(x1b, f1b, W2t, P2b, out_inv,
                                                  HID4, HID4, HID4);
    }
    gather_nodes<HID4, 1><<<N_NODES, HID4 / 2, 0, stream>>>(P2b, off, es23, in_inv, x2b);

    // conv3
    {
        dim3 grid(M_PAD / 128, OUT_DIM / 128);
        gemm_mfma<0, 1><<<grid, 256, 0, stream>>>(x2b, nullptr, W3t, Q3b, out_inv,
                                                  HID4, 0, OUT_DIM);
    }
    gather_nodes<OUT_DIM, 1><<<N_NODES, OUT_DIM / 2, 0, stream>>>(Q3b, off, es23, in_inv, x3b);

    // readout + normalize
    readout_sum<<<(N_NODES + RO_NPB - 1) / RO_NPB, 128, 0, stream>>>(x3b, gid, ro);
    normalize_out<<<N_GRAPHS, 128, 0, stream>>>(ro, out);
}

// Round 8
// 298.303 us; speedup vs baseline: 3.7241x; 1.0005x over previous
//
#include <hip/hip_runtime.h>

#define N_NODES 40000
#define M_PAD   40064   // 313 * 128
#define N_EDGES 320000
#define N_GRAPHS 64
#define IN_DIM 128
#define HID4 256
#define OUT_DIM 128
#define LN_EPS 1e-5f

typedef short  s16x8  __attribute__((ext_vector_type(8)));
typedef short  s16x4  __attribute__((ext_vector_type(4)));
typedef __bf16 bf16x8 __attribute__((ext_vector_type(8)));
typedef float  f32x4  __attribute__((ext_vector_type(4)));

__device__ __forceinline__ unsigned short f2b(float f) {
    unsigned int u = __builtin_bit_cast(unsigned int, f);
    u += 0x7fffu + ((u >> 16) & 1u);   // round-to-nearest-even
    return (unsigned short)(u >> 16);
}
__device__ __forceinline__ float b2f(unsigned short h) {
    unsigned int u = (unsigned int)h << 16;
    return __builtin_bit_cast(float, u);
}

// direct global->LDS 16B DMA; lds base must be wave-uniform, HW scatters lane*16
__device__ __forceinline__ void gll16(const unsigned short* g, short* lds_base) {
    __builtin_amdgcn_global_load_lds(
        (const __attribute__((address_space(1))) unsigned int*)g,
        (__attribute__((address_space(3))) unsigned int*)lds_base, 16, 0, 0);
}

// ---------------- fused prep: x->bf16, weights->bf16 transposed, edge ew + degree histograms ----

#define XN (N_NODES * IN_DIM)          // 5,120,000
#define WN 229376                      // 32768*3 + 131072
#define PREP_TOT (XN + WN + N_EDGES)

__global__ void prep_all(const float* __restrict__ x, const float* __restrict__ W1,
                         const float* __restrict__ fc1, const float* __restrict__ W2,
                         const float* __restrict__ W3, const float* __restrict__ w,
                         const int* __restrict__ src, const int* __restrict__ dst,
                         unsigned short* __restrict__ xb, unsigned short* __restrict__ W1t,
                         unsigned short* __restrict__ fc1t, unsigned short* __restrict__ W2t,
                         unsigned short* __restrict__ W3t, float* __restrict__ ew,
                         int* __restrict__ cnt_out, int* __restrict__ cnt_in) {
    int idx = blockIdx.x * 256 + threadIdx.x;
    if (idx < XN) { xb[idx] = f2b(x[idx]); return; }
    int j = idx - XN;
    if (j < 32768) { int k = j >> 8, n = j & 255; W1t[n * 128 + k] = f2b(W1[j]); return; }
    j -= 32768;
    if (j < 32768) { int k = j >> 8, n = j & 255; fc1t[n * 128 + k] = f2b(fc1[j]); return; }
    j -= 32768;
    if (j < 131072) { int k = j >> 8, n = j & 255; W2t[n * 512 + k] = f2b(W2[j]); return; }
    j -= 131072;
    if (j < 32768) { int k = j >> 7, n = j & 127; W3t[n * 256 + k] = f2b(W3[j]); return; }
    j -= 32768;
    if (j < N_EDGES) {
        float4 v = ((const float4*)w)[j];
        ew[j] = fmaxf(fmaxf(v.x, v.y), fmaxf(v.z, v.w));
        atomicAdd(&cnt_out[src[j]], 1);
        atomicAdd(&cnt_in[dst[j]], 1);
    }
}

// stage 1: 40 blocks x 256 threads, block b sums cnt[b*1000 .. b*1000+999]
__global__ void scan_part(const int* __restrict__ cnt, int* __restrict__ partial) {
    int b = blockIdx.x;
    int s = 0;
    for (int i = threadIdx.x; i < 1000; i += 256) s += cnt[b * 1000 + i];
#pragma unroll
    for (int m = 1; m < 64; m <<= 1) s += __shfl_xor(s, m);
    __shared__ int wsm[4];
    if ((threadIdx.x & 63) == 0) wsm[threadIdx.x >> 6] = s;
    __syncthreads();
    if (threadIdx.x == 0) partial[b] = wsm[0] + wsm[1] + wsm[2] + wsm[3];
}

// stage 2: 40 blocks x 1024 threads; exclusive scan -> off ; also inv-sqrt degrees
__global__ void scan_final(const int* __restrict__ cnt_in, const int* __restrict__ cnt_out,
                           const int* __restrict__ partial, int* __restrict__ off,
                           float* __restrict__ out_inv, float* __restrict__ in_inv) {
    int b = blockIdx.x, tid = threadIdx.x;
    int lane = tid & 63, wv = tid >> 6;
    int pre = 0;
    for (int j = 0; j < b; ++j) pre += partial[j];
    int i = b * 1000 + tid;
    int v = (tid < 1000) ? cnt_in[i] : 0;
    int x = v;
#pragma unroll
    for (int ofs = 1; ofs < 64; ofs <<= 1) {
        int t = __shfl_up(x, ofs);
        if (lane >= ofs) x += t;
    }
    __shared__ int wsum[16];
    if (lane == 63) wsum[wv] = x;
    __syncthreads();
    if (wv == 0 && lane < 16) {
        int s = wsum[lane];
#pragma unroll
        for (int ofs = 1; ofs < 16; ofs <<= 1) {
            int t = __shfl_up(s, ofs);
            if (lane >= ofs) s += t;
        }
        wsum[lane] = s;
    }
    __syncthreads();
    int incl = pre + (wv > 0 ? wsum[wv - 1] : 0) + x;
    if (tid < 1000) {
        off[i] = incl - v;   // exclusive
        in_inv[i] = rsqrtf(fmaxf((float)v, 1.0f));
        out_inv[i] = rsqrtf(fmaxf((float)cnt_out[i], 1.0f));
    }
    if (b == 39 && tid == 999) off[N_NODES] = incl;
}

// consumes cnt_in as countdown cursor; emits packed (src, weight) records
__global__ void csr_fill(const int* __restrict__ src, const int* __restrict__ dst,
                         const float* __restrict__ ew, const float* __restrict__ out_inv,
                         const int* __restrict__ off, int* __restrict__ cnt_in,
                         int2* __restrict__ es1, int2* __restrict__ es23) {
    int e = blockIdx.x * 256 + threadIdx.x;
    if (e >= N_EDGES) return;
    int d = dst[e];
    int slot = off[d] + atomicSub(&cnt_in[d], 1) - 1;
    int s = src[e];
    float wv = ew[e];
    es1[slot] = make_int2(s, __float_as_int(wv * out_inv[s]));
    es23[slot] = make_int2(s, __float_as_int(wv));
}

// ---------------- gather aggregation (block per dst node), packed edges ----------------

template <int D, int RELU>
__global__ void gather_nodes(const unsigned short* __restrict__ h, const int* __restrict__ off,
                             const int2* __restrict__ eg, const float* __restrict__ scale,
                             unsigned short* __restrict__ outb) {
    int n = blockIdx.x;
    int t = threadIdx.x;  // D/2 threads
    int b = off[n], e = off[n + 1];
    const unsigned int* hu = (const unsigned int*)h;
    float a0 = 0.0f, a1 = 0.0f;
    int i = b;
    for (; i + 3 < e; i += 4) {
        int2 e0 = eg[i], e1 = eg[i + 1], e2 = eg[i + 2], e3 = eg[i + 3];
        unsigned int p0 = hu[(size_t)e0.x * (D / 2) + t];
        unsigned int p1 = hu[(size_t)e1.x * (D / 2) + t];
        unsigned int p2 = hu[(size_t)e2.x * (D / 2) + t];
        unsigned int p3 = hu[(size_t)e3.x * (D / 2) + t];
        float w0 = __int_as_float(e0.y), w1 = __int_as_float(e1.y);
        float w2 = __int_as_float(e2.y), w3 = __int_as_float(e3.y);
        a0 += w0 * b2f((unsigned short)p0) + w1 * b2f((unsigned short)p1)
            + w2 * b2f((unsigned short)p2) + w3 * b2f((unsigned short)p3);
        a1 += w0 * b2f((unsigned short)(p0 >> 16)) + w1 * b2f((unsigned short)(p1 >> 16))
            + w2 * b2f((unsigned short)(p2 >> 16)) + w3 * b2f((unsigned short)(p3 >> 16));
    }
    for (; i < e; ++i) {
        int2 ee = eg[i];
        unsigned int p = hu[(size_t)ee.x * (D / 2) + t];
        float w0 = __int_as_float(ee.y);
        a0 += w0 * b2f((unsigned short)p);
        a1 += w0 * b2f((unsigned short)(p >> 16));
    }
    float sc = scale[n];
    a0 *= sc; a1 *= sc;
    if (RELU) { a0 = fmaxf(a0, 0.0f); a1 = fmaxf(a1, 0.0f); }
    unsigned int o = (unsigned int)f2b(a0) | ((unsigned int)f2b(a1) << 16);
    ((unsigned int*)outb)[(size_t)n * (D / 2) + t] = o;
}

// ---------------- MFMA bf16 GEMM core: 128x128 tile, BK=32, global_load_lds staging ------
// LDS tiles are UNPADDED [128][32] shorts (global_load_lds scatters lane*16B; m104/m108).

__device__ __forceinline__ void gemm_core(short* As, short* Bs,
    const unsigned short* __restrict__ A, const unsigned short* __restrict__ A2,
    const unsigned short* __restrict__ Bt, unsigned short* __restrict__ C,
    const float* __restrict__ rowScaleC, int K1, int K2, int N,
    int relu, int scaleC, int m0, int n0) {
    int tid = threadIdx.x;
    int lane = tid & 63, wave = tid >> 6;
    int wm = (wave >> 1) * 64, wn = (wave & 1) * 64;
    int quad = lane >> 4, r16 = lane & 15;
    const int K = K1 + K2;
    f32x4 acc[4][4] = {};
    int lrow = wave * 16 + (lane >> 2);   // row within 64-row half (staging)
    int kc = (lane & 3) * 8;              // bf16 chunk offset within BK=32
    short* ldsA = As + wave * 512;        // wave-uniform base; +h*2048 per half
    short* ldsB = Bs + wave * 512;

    for (int k0 = 0; k0 < K; k0 += 32) {
        int kk = k0 + kc;
#pragma unroll
        for (int h = 0; h < 2; ++h) {
            int r = h * 64 + lrow;
            const unsigned short* Ap = (kk < K1)
                ? A  + (size_t)(m0 + r) * K1 + kk
                : A2 + (size_t)(m0 + r) * K2 + (kk - K1);
            gll16(Ap, ldsA + h * 2048);
            gll16(Bt + (size_t)(n0 + r) * K + kk, ldsB + h * 2048);
        }
        __syncthreads();
        s16x8 af[4], bfr[4];
#pragma unroll
        for (int i = 0; i < 4; ++i)
            af[i] = *(const s16x8*)(As + (wm + i * 16 + r16) * 32 + quad * 8);
#pragma unroll
        for (int j = 0; j < 4; ++j)
            bfr[j] = *(const s16x8*)(Bs + (wn + j * 16 + r16) * 32 + quad * 8);
#pragma unroll
        for (int i = 0; i < 4; ++i)
#pragma unroll
            for (int j = 0; j < 4; ++j)
                acc[i][j] = __builtin_amdgcn_mfma_f32_16x16x32_bf16(
                    __builtin_bit_cast(bf16x8, af[i]), __builtin_bit_cast(bf16x8, bfr[j]),
                    acc[i][j], 0, 0, 0);
        __syncthreads();
    }

    // C/D layout: col = lane&15, row = quad*4 + reg
#pragma unroll
    for (int i = 0; i < 4; ++i) {
        int mbase = m0 + wm + i * 16 + quad * 4;
#pragma unroll
        for (int r = 0; r < 4; ++r) {
            int m = mbase + r;
            float sc = scaleC ? rowScaleC[m] : 1.0f;
#pragma unroll
            for (int j = 0; j < 4; ++j) {
                float v = acc[i][j][r] * sc;
                if (relu) v = fmaxf(v, 0.0f);
                C[(size_t)m * N + n0 + wn + j * 16 + r16] = f2b(v);
            }
        }
    }
}

template <int RELU, int SCALE_C>
__global__ __launch_bounds__(256) void gemm_mfma(
    const unsigned short* __restrict__ A, const unsigned short* __restrict__ A2,
    const unsigned short* __restrict__ Bt, unsigned short* __restrict__ C,
    const float* __restrict__ rowScaleC, int K1, int K2, int N) {
    __shared__ short As[4096];
    __shared__ short Bs[4096];
    gemm_core(As, Bs, A, A2, Bt, C, rowScaleC, K1, K2, N, RELU, SCALE_C,
              blockIdx.x * 128, blockIdx.y * 128);
}

// dual GEMM: conv1 (z=0, relu) + fc1 (z=1) ; K=128, N=256
__global__ __launch_bounds__(256) void gemm_dual(
    const unsigned short* __restrict__ A0, const unsigned short* __restrict__ B0,
    unsigned short* __restrict__ C0,
    const unsigned short* __restrict__ A1, const unsigned short* __restrict__ B1,
    unsigned short* __restrict__ C1) {
    __shared__ short As[4096];
    __shared__ short Bs[4096];
    const unsigned short* A  = blockIdx.z ? A1 : A0;
    const unsigned short* Bt = blockIdx.z ? B1 : B0;
    unsigned short* C        = blockIdx.z ? C1 : C0;
    gemm_core(As, Bs, A, A, Bt, C, nullptr, 128, 0, 256, blockIdx.z == 0, 0,
              blockIdx.x * 128, blockIdx.y * 128);
}

// ---------------- LayerNorm + ReLU, in-place bf16 (wave per row, 256 cols) ----------------

__global__ void ln_relu_bf16(unsigned short* __restrict__ f, const float* __restrict__ gamma,
                             const float* __restrict__ beta) {
    int row = (blockIdx.x * 256 + threadIdx.x) >> 6;
    int lane = threadIdx.x & 63;
    if (row >= N_NODES) return;
    s16x4* fr = (s16x4*)(f + (size_t)row * HID4);
    s16x4 pv = fr[lane];
    float v0 = b2f((unsigned short)pv[0]);
    float v1 = b2f((unsigned short)pv[1]);
    float v2 = b2f((unsigned short)pv[2]);
    float v3 = b2f((unsigned short)pv[3]);
    float sum = v0 + v1 + v2 + v3;
#pragma unroll
    for (int m = 1; m < 64; m <<= 1) sum += __shfl_xor(sum, m);
    float mu = sum * (1.0f / HID4);
    float d0 = v0 - mu, d1 = v1 - mu, d2 = v2 - mu, d3 = v3 - mu;
    float sq = d0 * d0 + d1 * d1 + d2 * d2 + d3 * d3;
#pragma unroll
    for (int m = 1; m < 64; m <<= 1) sq += __shfl_xor(sq, m);
    float rs = rsqrtf(sq * (1.0f / HID4) + LN_EPS);
    int c = lane * 4;
    s16x4 ov;
    ov[0] = (short)f2b(fmaxf(d0 * rs * gamma[c + 0] + beta[c + 0], 0.0f));
    ov[1] = (short)f2b(fmaxf(d1 * rs * gamma[c + 1] + beta[c + 1], 0.0f));
    ov[2] = (short)f2b(fmaxf(d2 * rs * gamma[c + 2] + beta[c + 2], 0.0f));
    ov[3] = (short)f2b(fmaxf(d3 * rs * gamma[c + 3] + beta[c + 3], 0.0f));
    fr[lane] = ov;
}

// ---------------- readout (16 nodes/block, bf16 in) ----------------

#define RO_NPB 16

__global__ void readout_sum(const unsigned short* __restrict__ x3, const int* __restrict__ gid,
                            float* __restrict__ ro) {
    int d = threadIdx.x;  // 0..127
    int n0 = blockIdx.x * RO_NPB;
    int n1 = n0 + RO_NPB;
    if (n1 > N_NODES) n1 = N_NODES;
    float acc = 0.0f;
    int cur = gid[n0];
    for (int n = n0; n < n1; ++n) {
        int g = gid[n];
        if (g != cur) {
            atomicAdd(&ro[cur * OUT_DIM + d], acc);
            acc = 0.0f;
            cur = g;
        }
        acc += b2f(x3[(size_t)n * OUT_DIM + d]);
    }
    atomicAdd(&ro[cur * OUT_DIM + d], acc);
}

__global__ void normalize_out(const float* __restrict__ ro, float* __restrict__ out) {
    int g = blockIdx.x;
    int d = threadIdx.x;  // 128 threads = 2 waves
    float v = ro[g * OUT_DIM + d];
    float ss = v * v;
#pragma unroll
    for (int m = 1; m < 64; m <<= 1) ss += __shfl_xor(ss, m);
    __shared__ float s2[2];
    if ((d & 63) == 0) s2[d >> 6] = ss;
    __syncthreads();
    float tot = s2[0] + s2[1];
    float norm = fmaxf(sqrtf(tot), 1e-12f);
    out[g * OUT_DIM + d] = v / norm;
}

// ---------------- launch ----------------

extern "C" void kernel_launch(void* const* d_in, const int* in_sizes, int n_in,
                              void* d_out, int out_size, void* d_ws, size_t ws_size,
                              hipStream_t stream) {
    const float* x    = (const float*)d_in[0];
    const float* w    = (const float*)d_in[1];
    const float* W1   = (const float*)d_in[2];
    const float* fc1W = (const float*)d_in[3];
    const float* gam  = (const float*)d_in[4];
    const float* bet  = (const float*)d_in[5];
    const float* W2   = (const float*)d_in[6];
    const float* W3   = (const float*)d_in[7];
    const int* src = (const int*)d_in[8];
    const int* dst = (const int*)d_in[9];
    const int* gid = (const int*)d_in[10];
    float* out = (float*)d_out;

    float* ws = (float*)d_ws;
    float* out_inv = ws + 0;                                 // 40000
    float* in_inv  = ws + 40000;                             // 40000
    float* ew      = ws + 80000;                             // 320000
    int*   cnt_out = (int*)(ws + 400000);                    // 40000 (memset group start)
    int*   cnt_in  = (int*)(ws + 440000);                    // 40000 (memset group)
    float* ro      = ws + 480000;                            // 8192 (memset group end)
    unsigned short* W1t  = (unsigned short*)(ws + 488192);   // [256][128]
    unsigned short* fc1t = (unsigned short*)(ws + 504576);   // [256][128]
    unsigned short* W2t  = (unsigned short*)(ws + 520960);   // [256][512]
    unsigned short* W3t  = (unsigned short*)(ws + 586496);   // [128][256]
    int*   partial = (int*)(ws + 602880);                    // 40
    int*   off     = (int*)(ws + 602920);                    // 40001
    int2*  es1     = (int2*)(ws + 642922);                   // 320000 int2
    int2*  es23    = (int2*)(ws + 1282922);                  // 320000 int2
    unsigned short* xb    = (unsigned short*)(ws + 1923000); // [M_PAD][128] ; later Q3b
    unsigned short* Q3b   = xb;
    unsigned short* agg1b = (unsigned short*)(ws + 4487100); // [M_PAD][128..256] ; later x2b
    unsigned short* x2b   = agg1b;
    unsigned short* x1b   = (unsigned short*)(ws + 9615300); // [M_PAD][256] ; later x3 bf16
    unsigned short* x3b   = x1b;
    unsigned short* f1b   = (unsigned short*)(ws + 14743500);// [M_PAD][256]
    unsigned short* P2b   = (unsigned short*)(ws + 19871700);// [M_PAD][256]

    // one memset covers cnt_out | cnt_in | ro (contiguous)
    hipMemsetAsync(cnt_out, 0, (2 * 40000 + N_GRAPHS * OUT_DIM) * sizeof(float), stream);

    // fused conversions + edge weights + degree histograms
    prep_all<<<(PREP_TOT + 255) / 256, 256, 0, stream>>>(x, W1, fc1W, W2, W3, w, src, dst,
                                                         xb, W1t, fc1t, W2t, W3t, ew,
                                                         cnt_out, cnt_in);
    scan_part<<<40, 256, 0, stream>>>(cnt_in, partial);
    scan_final<<<40, 1024, 0, stream>>>(cnt_in, cnt_out, partial, off, out_inv, in_inv);
    csr_fill<<<(N_EDGES + 255) / 256, 256, 0, stream>>>(src, dst, ew, out_inv, off, cnt_in,
                                                        es1, es23);

    // conv1 gather, then fused conv1+fc1 GEMM
    gather_nodes<IN_DIM, 0><<<N_NODES, IN_DIM / 2, 0, stream>>>(xb, off, es1, in_inv, agg1b);
    {
        dim3 grid(M_PAD / 128, HID4 / 128, 2);
        gemm_dual<<<grid, 256, 0, stream>>>(agg1b, W1t, x1b, xb, fc1t, f1b);
    }
    ln_relu_bf16<<<N_NODES / 4, 256, 0, stream>>>(f1b, gam, bet);

    // conv2
    {
        dim3 grid(M_PAD / 128, HID4 / 128);
        gemm_mfma<0, 1><<<grid, 256, 0, stream>>>(x1b, f1b, W2t, P2b, out_inv,
                                                  HID4, HID4, HID4);
    }
    gather_nodes<HID4, 1><<<N_NODES, HID4 / 2, 0, stream>>>(P2b, off, es23, in_inv, x2b);

    // conv3
    {
        dim3 grid(M_PAD / 128, OUT_DIM / 128);
        gemm_mfma<0, 1><<<grid, 256, 0, stream>>>(x2b, nullptr, W3t, Q3b, out_inv,
                                                  HID4, 0, OUT_DIM);
    }
    gather_nodes<OUT_DIM, 1><<<N_NODES, OUT_DIM / 2, 0, stream>>>(Q3b, off, es23, in_inv, x3b);

    // readout + normalize
    readout_sum<<<(N_NODES + RO_NPB - 1) / RO_NPB, 128, 0, stream>>>(x3b, gid, ro);
    normalize_out<<<N_GRAPHS, 128, 0, stream>>>(ro, out);
}

// Round 9
// 285.615 us; speedup vs baseline: 3.8895x; 1.0444x over previous
//
#include <hip/hip_runtime.h>

#define N_NODES 40000
#define M_PAD   40064   // 313 * 128
#define N_EDGES 320000
#define N_GRAPHS 64
#define IN_DIM 128
#define HID4 256
#define OUT_DIM 128
#define LN_EPS 1e-5f

typedef short  s16x8  __attribute__((ext_vector_type(8)));
typedef __bf16 bf16x8 __attribute__((ext_vector_type(8)));
typedef float  f32x4  __attribute__((ext_vector_type(4)));

__device__ __forceinline__ unsigned short f2b(float f) {
    unsigned int u = __builtin_bit_cast(unsigned int, f);
    u += 0x7fffu + ((u >> 16) & 1u);   // round-to-nearest-even
    return (unsigned short)(u >> 16);
}
__device__ __forceinline__ float b2f(unsigned short h) {
    unsigned int u = (unsigned int)h << 16;
    return __builtin_bit_cast(float, u);
}

// direct global->LDS 16B DMA; lds base wave-uniform, HW scatters lane*16
__device__ __forceinline__ void gll16(const unsigned short* g, short* lds_base) {
    __builtin_amdgcn_global_load_lds(
        (const __attribute__((address_space(1))) unsigned int*)g,
        (__attribute__((address_space(3))) unsigned int*)lds_base, 16, 0, 0);
}

// ---------------- fused prep: x->bf16, weights->bf16 transposed, edge ew + degree histograms ----

#define XN (N_NODES * IN_DIM)          // 5,120,000
#define WN 229376                      // 32768*3 + 131072
#define PREP_TOT (XN + WN + N_EDGES)

__global__ void prep_all(const float* __restrict__ x, const float* __restrict__ W1,
                         const float* __restrict__ fc1, const float* __restrict__ W2,
                         const float* __restrict__ W3, const float* __restrict__ w,
                         const int* __restrict__ src, const int* __restrict__ dst,
                         unsigned short* __restrict__ xb, unsigned short* __restrict__ W1t,
                         unsigned short* __restrict__ fc1t, unsigned short* __restrict__ W2t,
                         unsigned short* __restrict__ W3t, float* __restrict__ ew,
                         int* __restrict__ cnt_out, int* __restrict__ cnt_in) {
    int idx = blockIdx.x * 256 + threadIdx.x;
    if (idx < XN) { xb[idx] = f2b(x[idx]); return; }
    int j = idx - XN;
    if (j < 32768) { int k = j >> 8, n = j & 255; W1t[n * 128 + k] = f2b(W1[j]); return; }
    j -= 32768;
    if (j < 32768) { int k = j >> 8, n = j & 255; fc1t[n * 128 + k] = f2b(fc1[j]); return; }
    j -= 32768;
    if (j < 131072) { int k = j >> 8, n = j & 255; W2t[n * 512 + k] = f2b(W2[j]); return; }
    j -= 131072;
    if (j < 32768) { int k = j >> 7, n = j & 127; W3t[n * 256 + k] = f2b(W3[j]); return; }
    j -= 32768;
    if (j < N_EDGES) {
        float4 v = ((const float4*)w)[j];
        ew[j] = fmaxf(fmaxf(v.x, v.y), fmaxf(v.z, v.w));
        atomicAdd(&cnt_out[src[j]], 1);
        atomicAdd(&cnt_in[dst[j]], 1);
    }
}

// stage 1: 40 blocks x 256 threads, block b sums cnt[b*1000 .. b*1000+999]
__global__ void scan_part(const int* __restrict__ cnt, int* __restrict__ partial) {
    int b = blockIdx.x;
    int s = 0;
    for (int i = threadIdx.x; i < 1000; i += 256) s += cnt[b * 1000 + i];
#pragma unroll
    for (int m = 1; m < 64; m <<= 1) s += __shfl_xor(s, m);
    __shared__ int wsm[4];
    if ((threadIdx.x & 63) == 0) wsm[threadIdx.x >> 6] = s;
    __syncthreads();
    if (threadIdx.x == 0) partial[b] = wsm[0] + wsm[1] + wsm[2] + wsm[3];
}

// stage 2: 40 blocks x 1024 threads; exclusive scan -> off ; also inv-sqrt degrees
__global__ void scan_final(const int* __restrict__ cnt_in, const int* __restrict__ cnt_out,
                           const int* __restrict__ partial, int* __restrict__ off,
                           float* __restrict__ out_inv, float* __restrict__ in_inv) {
    int b = blockIdx.x, tid = threadIdx.x;
    int lane = tid & 63, wv = tid >> 6;
    int pre = 0;
    for (int j = 0; j < b; ++j) pre += partial[j];
    int i = b * 1000 + tid;
    int v = (tid < 1000) ? cnt_in[i] : 0;
    int x = v;
#pragma unroll
    for (int ofs = 1; ofs < 64; ofs <<= 1) {
        int t = __shfl_up(x, ofs);
        if (lane >= ofs) x += t;
    }
    __shared__ int wsum[16];
    if (lane == 63) wsum[wv] = x;
    __syncthreads();
    if (wv == 0 && lane < 16) {
        int s = wsum[lane];
#pragma unroll
        for (int ofs = 1; ofs < 16; ofs <<= 1) {
            int t = __shfl_up(s, ofs);
            if (lane >= ofs) s += t;
        }
        wsum[lane] = s;
    }
    __syncthreads();
    int incl = pre + (wv > 0 ? wsum[wv - 1] : 0) + x;
    if (tid < 1000) {
        off[i] = incl - v;   // exclusive
        in_inv[i] = rsqrtf(fmaxf((float)v, 1.0f));
        out_inv[i] = rsqrtf(fmaxf((float)cnt_out[i], 1.0f));
    }
    if (b == 39 && tid == 999) off[N_NODES] = incl;
}

// consumes cnt_in as countdown cursor; emits packed (src, weight) records
__global__ void csr_fill(const int* __restrict__ src, const int* __restrict__ dst,
                         const float* __restrict__ ew, const float* __restrict__ out_inv,
                         const int* __restrict__ off, int* __restrict__ cnt_in,
                         int2* __restrict__ es1, int2* __restrict__ es23) {
    int e = blockIdx.x * 256 + threadIdx.x;
    if (e >= N_EDGES) return;
    int d = dst[e];
    int slot = off[d] + atomicSub(&cnt_in[d], 1) - 1;
    int s = src[e];
    float wv = ew[e];
    es1[slot] = make_int2(s, __float_as_int(wv * out_inv[s]));
    es23[slot] = make_int2(s, __float_as_int(wv));
}

// ---------------- gather aggregation (block per dst node), packed edges ----------------

template <int D, int RELU>
__global__ void gather_nodes(const unsigned short* __restrict__ h, const int* __restrict__ off,
                             const int2* __restrict__ eg, const float* __restrict__ scale,
                             unsigned short* __restrict__ outb) {
    int n = blockIdx.x;
    int t = threadIdx.x;  // D/2 threads
    int b = off[n], e = off[n + 1];
    const unsigned int* hu = (const unsigned int*)h;
    float a0 = 0.0f, a1 = 0.0f;
    int i = b;
    for (; i + 3 < e; i += 4) {
        int2 e0 = eg[i], e1 = eg[i + 1], e2 = eg[i + 2], e3 = eg[i + 3];
        unsigned int p0 = hu[(size_t)e0.x * (D / 2) + t];
        unsigned int p1 = hu[(size_t)e1.x * (D / 2) + t];
        unsigned int p2 = hu[(size_t)e2.x * (D / 2) + t];
        unsigned int p3 = hu[(size_t)e3.x * (D / 2) + t];
        float w0 = __int_as_float(e0.y), w1 = __int_as_float(e1.y);
        float w2 = __int_as_float(e2.y), w3 = __int_as_float(e3.y);
        a0 += w0 * b2f((unsigned short)p0) + w1 * b2f((unsigned short)p1)
            + w2 * b2f((unsigned short)p2) + w3 * b2f((unsigned short)p3);
        a1 += w0 * b2f((unsigned short)(p0 >> 16)) + w1 * b2f((unsigned short)(p1 >> 16))
            + w2 * b2f((unsigned short)(p2 >> 16)) + w3 * b2f((unsigned short)(p3 >> 16));
    }
    for (; i < e; ++i) {
        int2 ee = eg[i];
        unsigned int p = hu[(size_t)ee.x * (D / 2) + t];
        float w0 = __int_as_float(ee.y);
        a0 += w0 * b2f((unsigned short)p);
        a1 += w0 * b2f((unsigned short)(p >> 16));
    }
    float sc = scale[n];
    a0 *= sc; a1 *= sc;
    if (RELU) { a0 = fmaxf(a0, 0.0f); a1 = fmaxf(a1, 0.0f); }
    unsigned int o = (unsigned int)f2b(a0) | ((unsigned int)f2b(a1) << 16);
    ((unsigned int*)outb)[(size_t)n * (D / 2) + t] = o;
}

// ---------------- gather conv3 + fused readout (8 nodes/block, run-length atomics) ------

#define G3_NPB 8

__global__ void gather3_ro(const unsigned short* __restrict__ h, const int* __restrict__ off,
                           const int2* __restrict__ eg, const float* __restrict__ scale,
                           const int* __restrict__ gid, float* __restrict__ ro) {
    int t = threadIdx.x;  // 64 threads; cols 2t, 2t+1 (D=128)
    int n0 = blockIdx.x * G3_NPB;
    int n1 = n0 + G3_NPB;
    if (n1 > N_NODES) n1 = N_NODES;
    const unsigned int* hu = (const unsigned int*)h;
    float r0 = 0.0f, r1 = 0.0f;
    int cur = gid[n0];
    for (int n = n0; n < n1; ++n) {
        int g = gid[n];
        if (g != cur) {
            atomicAdd(&ro[cur * OUT_DIM + 2 * t], r0);
            atomicAdd(&ro[cur * OUT_DIM + 2 * t + 1], r1);
            r0 = r1 = 0.0f;
            cur = g;
        }
        int b = off[n], e = off[n + 1];
        float a0 = 0.0f, a1 = 0.0f;
        int i = b;
        for (; i + 3 < e; i += 4) {
            int2 e0 = eg[i], e1 = eg[i + 1], e2 = eg[i + 2], e3 = eg[i + 3];
            unsigned int p0 = hu[(size_t)e0.x * 64 + t];
            unsigned int p1 = hu[(size_t)e1.x * 64 + t];
            unsigned int p2 = hu[(size_t)e2.x * 64 + t];
            unsigned int p3 = hu[(size_t)e3.x * 64 + t];
            float w0 = __int_as_float(e0.y), w1 = __int_as_float(e1.y);
            float w2 = __int_as_float(e2.y), w3 = __int_as_float(e3.y);
            a0 += w0 * b2f((unsigned short)p0) + w1 * b2f((unsigned short)p1)
                + w2 * b2f((unsigned short)p2) + w3 * b2f((unsigned short)p3);
            a1 += w0 * b2f((unsigned short)(p0 >> 16)) + w1 * b2f((unsigned short)(p1 >> 16))
                + w2 * b2f((unsigned short)(p2 >> 16)) + w3 * b2f((unsigned short)(p3 >> 16));
        }
        for (; i < e; ++i) {
            int2 ee = eg[i];
            unsigned int p = hu[(size_t)ee.x * 64 + t];
            float w0 = __int_as_float(ee.y);
            a0 += w0 * b2f((unsigned short)p);
            a1 += w0 * b2f((unsigned short)(p >> 16));
        }
        float sc = scale[n];
        r0 += fmaxf(a0 * sc, 0.0f);
        r1 += fmaxf(a1 * sc, 0.0f);
    }
    atomicAdd(&ro[cur * OUT_DIM + 2 * t], r0);
    atomicAdd(&ro[cur * OUT_DIM + 2 * t + 1], r1);
}

// ---------------- MFMA bf16 GEMM core: 128x128 tile, BK=32, global_load_lds staging ------

__device__ __forceinline__ void gemm_core(short* As, short* Bs,
    const unsigned short* __restrict__ A, const unsigned short* __restrict__ A2,
    const unsigned short* __restrict__ Bt, unsigned short* __restrict__ C,
    const float* __restrict__ rowScaleC, int K1, int K2, int N,
    int relu, int scaleC, int m0, int n0) {
    int tid = threadIdx.x;
    int lane = tid & 63, wave = tid >> 6;
    int wm = (wave >> 1) * 64, wn = (wave & 1) * 64;
    int quad = lane >> 4, r16 = lane & 15;
    const int K = K1 + K2;
    f32x4 acc[4][4] = {};
    int lrow = wave * 16 + (lane >> 2);
    int kc = (lane & 3) * 8;
    short* ldsA = As + wave * 512;
    short* ldsB = Bs + wave * 512;

    for (int k0 = 0; k0 < K; k0 += 32) {
        int kk = k0 + kc;
#pragma unroll
        for (int h = 0; h < 2; ++h) {
            int r = h * 64 + lrow;
            const unsigned short* Ap = (kk < K1)
                ? A  + (size_t)(m0 + r) * K1 + kk
                : A2 + (size_t)(m0 + r) * K2 + (kk - K1);
            gll16(Ap, ldsA + h * 2048);
            gll16(Bt + (size_t)(n0 + r) * K + kk, ldsB + h * 2048);
        }
        __syncthreads();
        s16x8 af[4], bfr[4];
#pragma unroll
        for (int i = 0; i < 4; ++i)
            af[i] = *(const s16x8*)(As + (wm + i * 16 + r16) * 32 + quad * 8);
#pragma unroll
        for (int j = 0; j < 4; ++j)
            bfr[j] = *(const s16x8*)(Bs + (wn + j * 16 + r16) * 32 + quad * 8);
#pragma unroll
        for (int i = 0; i < 4; ++i)
#pragma unroll
            for (int j = 0; j < 4; ++j)
                acc[i][j] = __builtin_amdgcn_mfma_f32_16x16x32_bf16(
                    __builtin_bit_cast(bf16x8, af[i]), __builtin_bit_cast(bf16x8, bfr[j]),
                    acc[i][j], 0, 0, 0);
        __syncthreads();
    }

#pragma unroll
    for (int i = 0; i < 4; ++i) {
        int mbase = m0 + wm + i * 16 + quad * 4;
#pragma unroll
        for (int r = 0; r < 4; ++r) {
            int m = mbase + r;
            float sc = scaleC ? rowScaleC[m] : 1.0f;
#pragma unroll
            for (int j = 0; j < 4; ++j) {
                float v = acc[i][j][r] * sc;
                if (relu) v = fmaxf(v, 0.0f);
                C[(size_t)m * N + n0 + wn + j * 16 + r16] = f2b(v);
            }
        }
    }
}

template <int RELU, int SCALE_C>
__global__ __launch_bounds__(256) void gemm_mfma(
    const unsigned short* __restrict__ A, const unsigned short* __restrict__ A2,
    const unsigned short* __restrict__ Bt, unsigned short* __restrict__ C,
    const float* __restrict__ rowScaleC, int K1, int K2, int N) {
    __shared__ short As[4096];
    __shared__ short Bs[4096];
    gemm_core(As, Bs, A, A2, Bt, C, rowScaleC, K1, K2, N, RELU, SCALE_C,
              blockIdx.x * 128, blockIdx.y * 128);
}

// -------- dual GEMM, 128x256 tile, 512 threads (8 waves): conv1 (z=0, relu) / fc1+LN (z=1) ----
// K=128, N=256. Each block owns complete output rows -> LN computed in epilogue (z=1).

__global__ __launch_bounds__(512) void gemm_dual(
    const unsigned short* __restrict__ A0, const unsigned short* __restrict__ B0,
    unsigned short* __restrict__ C0,
    const unsigned short* __restrict__ A1, const unsigned short* __restrict__ B1,
    unsigned short* __restrict__ C1,
    const float* __restrict__ gamma, const float* __restrict__ beta) {
    __shared__ short As[4096];   // [128][32]
    __shared__ short Bs[8192];   // [256][32]
    __shared__ float lns[128][4];
    __shared__ float lnq[128][4];
    const unsigned short* A  = blockIdx.z ? A1 : A0;
    const unsigned short* Bt = blockIdx.z ? B1 : B0;
    unsigned short* C        = blockIdx.z ? C1 : C0;
    int tid = threadIdx.x;
    int lane = tid & 63, wave = tid >> 6;      // 0..7
    int wm = (wave >> 2) * 64, wn = (wave & 3) * 64;
    int quad = lane >> 4, r16 = lane & 15;
    int m0 = blockIdx.x * 128;
    f32x4 acc[4][4] = {};
    int lrow = lane >> 2;
    int kc = (lane & 3) * 8;
    short* ldsA = As + wave * 512;
    short* ldsB = Bs + wave * 512;

    for (int k0 = 0; k0 < 128; k0 += 32) {
        int kk = k0 + kc;
        int rr = wave * 16 + lrow;  // 0..127
        gll16(A + (size_t)(m0 + rr) * 128 + kk, ldsA);
        gll16(Bt + (size_t)rr * 128 + kk, ldsB);
        gll16(Bt + (size_t)(128 + rr) * 128 + kk, ldsB + 4096);
        __syncthreads();
        s16x8 af[4], bfr[4];
#pragma unroll
        for (int i = 0; i < 4; ++i)
            af[i] = *(const s16x8*)(As + (wm + i * 16 + r16) * 32 + quad * 8);
#pragma unroll
        for (int j = 0; j < 4; ++j)
            bfr[j] = *(const s16x8*)(Bs + (wn + j * 16 + r16) * 32 + quad * 8);
#pragma unroll
        for (int i = 0; i < 4; ++i)
#pragma unroll
            for (int j = 0; j < 4; ++j)
                acc[i][j] = __builtin_amdgcn_mfma_f32_16x16x32_bf16(
                    __builtin_bit_cast(bf16x8, af[i]), __builtin_bit_cast(bf16x8, bfr[j]),
                    acc[i][j], 0, 0, 0);
        __syncthreads();
    }

    if (blockIdx.z == 0) {
        // conv1: relu, store
#pragma unroll
        for (int i = 0; i < 4; ++i) {
            int mbase = m0 + wm + i * 16 + quad * 4;
#pragma unroll
            for (int r = 0; r < 4; ++r) {
                int m = mbase + r;
#pragma unroll
                for (int j = 0; j < 4; ++j)
                    C[(size_t)m * 256 + wn + j * 16 + r16] = f2b(fmaxf(acc[i][j][r], 0.0f));
            }
        }
    } else {
        // fc1: LayerNorm(affine) + relu from fp32 accumulators
#pragma unroll
        for (int i = 0; i < 4; ++i)
#pragma unroll
            for (int r = 0; r < 4; ++r) {
                float s = 0.0f, q = 0.0f;
#pragma unroll
                for (int j = 0; j < 4; ++j) { float v = acc[i][j][r]; s += v; q += v * v; }
#pragma unroll
                for (int m = 1; m < 16; m <<= 1) { s += __shfl_xor(s, m); q += __shfl_xor(q, m); }
                if (r16 == 0) {
                    int row = wm + i * 16 + quad * 4 + r;
                    lns[row][wave & 3] = s;
                    lnq[row][wave & 3] = q;
                }
            }
        __syncthreads();
#pragma unroll
        for (int i = 0; i < 4; ++i) {
#pragma unroll
            for (int r = 0; r < 4; ++r) {
                int row = wm + i * 16 + quad * 4 + r;
                float s = lns[row][0] + lns[row][1] + lns[row][2] + lns[row][3];
                float q = lnq[row][0] + lnq[row][1] + lnq[row][2] + lnq[row][3];
                float mu = s * (1.0f / HID4);
                float var = q * (1.0f / HID4) - mu * mu;
                float rs = rsqrtf(var + LN_EPS);
                int m = m0 + row;
#pragma unroll
                for (int j = 0; j < 4; ++j) {
                    int col = wn + j * 16 + r16;
                    float v = (acc[i][j][r] - mu) * rs * gamma[col] + beta[col];
                    C[(size_t)m * 256 + col] = f2b(fmaxf(v, 0.0f));
                }
            }
        }
    }
}

// ---------------- normalize ----------------

__global__ void normalize_out(const float* __restrict__ ro, float* __restrict__ out) {
    int g = blockIdx.x;
    int d = threadIdx.x;  // 128 threads = 2 waves
    float v = ro[g * OUT_DIM + d];
    float ss = v * v;
#pragma unroll
    for (int m = 1; m < 64; m <<= 1) ss += __shfl_xor(ss, m);
    __shared__ float s2[2];
    if ((d & 63) == 0) s2[d >> 6] = ss;
    __syncthreads();
    float tot = s2[0] + s2[1];
    float norm = fmaxf(sqrtf(tot), 1e-12f);
    out[g * OUT_DIM + d] = v / norm;
}

// ---------------- launch ----------------

extern "C" void kernel_launch(void* const* d_in, const int* in_sizes, int n_in,
                              void* d_out, int out_size, void* d_ws, size_t ws_size,
                              hipStream_t stream) {
    const float* x    = (const float*)d_in[0];
    const float* w    = (const float*)d_in[1];
    const float* W1   = (const float*)d_in[2];
    const float* fc1W = (const float*)d_in[3];
    const float* gam  = (const float*)d_in[4];
    const float* bet  = (const float*)d_in[5];
    const float* W2   = (const float*)d_in[6];
    const float* W3   = (const float*)d_in[7];
    const int* src = (const int*)d_in[8];
    const int* dst = (const int*)d_in[9];
    const int* gid = (const int*)d_in[10];
    float* out = (float*)d_out;

    float* ws = (float*)d_ws;
    float* out_inv = ws + 0;                                 // 40000
    float* in_inv  = ws + 40000;                             // 40000
    float* ew      = ws + 80000;                             // 320000
    int*   cnt_out = (int*)(ws + 400000);                    // 40000 (memset group start)
    int*   cnt_in  = (int*)(ws + 440000);                    // 40000 (memset group)
    float* ro      = ws + 480000;                            // 8192 (memset group end)
    unsigned short* W1t  = (unsigned short*)(ws + 488192);   // [256][128]
    unsigned short* fc1t = (unsigned short*)(ws + 504576);   // [256][128]
    unsigned short* W2t  = (unsigned short*)(ws + 520960);   // [256][512]
    unsigned short* W3t  = (unsigned short*)(ws + 586496);   // [128][256]
    int*   partial = (int*)(ws + 602880);                    // 40
    int*   off     = (int*)(ws + 602920);                    // 40001
    int2*  es1     = (int2*)(ws + 642922);                   // 320000 int2
    int2*  es23    = (int2*)(ws + 1282922);                  // 320000 int2
    unsigned short* xb    = (unsigned short*)(ws + 1923000); // [M_PAD][128] ; later Q3b
    unsigned short* Q3b   = xb;
    unsigned short* agg1b = (unsigned short*)(ws + 4487100); // [M_PAD][128..256] ; later x2b
    unsigned short* x2b   = agg1b;
    unsigned short* x1b   = (unsigned short*)(ws + 9615300); // [M_PAD][256]
    unsigned short* f1b   = (unsigned short*)(ws + 14743500);// [M_PAD][256]
    unsigned short* P2b   = (unsigned short*)(ws + 19871700);// [M_PAD][256]

    // one memset covers cnt_out | cnt_in | ro (contiguous)
    hipMemsetAsync(cnt_out, 0, (2 * 40000 + N_GRAPHS * OUT_DIM) * sizeof(float), stream);

    // fused conversions + edge weights + degree histograms
    prep_all<<<(PREP_TOT + 255) / 256, 256, 0, stream>>>(x, W1, fc1W, W2, W3, w, src, dst,
                                                         xb, W1t, fc1t, W2t, W3t, ew,
                                                         cnt_out, cnt_in);
    scan_part<<<40, 256, 0, stream>>>(cnt_in, partial);
    scan_final<<<40, 1024, 0, stream>>>(cnt_in, cnt_out, partial, off, out_inv, in_inv);
    csr_fill<<<(N_EDGES + 255) / 256, 256, 0, stream>>>(src, dst, ew, out_inv, off, cnt_in,
                                                        es1, es23);

    // conv1 gather, then fused conv1+fc1(+LN) GEMM (512-thread, 128x256 tile)
    gather_nodes<IN_DIM, 0><<<N_NODES, IN_DIM / 2, 0, stream>>>(xb, off, es1, in_inv, agg1b);
    {
        dim3 grid(M_PAD / 128, 1, 2);
        gemm_dual<<<grid, 512, 0, stream>>>(agg1b, W1t, x1b, xb, fc1t, f1b, gam, bet);
    }

    // conv2
    {
        dim3 grid(M_PAD / 128, HID4 / 128);
        gemm_mfma<0, 1><<<grid, 256, 0, stream>>>(x1b, f1b, W2t, P2b, out_inv,
                                                  HID4, HID4, HID4);
    }
    gather_nodes<HID4, 1><<<N_NODES, HID4 / 2, 0, stream>>>(P2b, off, es23, in_inv, x2b);

    // conv3
    {
        dim3 grid(M_PAD / 128, OUT_DIM / 128);
        gemm_mfma<0, 1><<<grid, 256, 0, stream>>>(x2b, nullptr, W3t, Q3b, out_inv,
                                                  HID4, 0, OUT_DIM);
    }
    // conv3 gather fused with readout (x3 never materialized)
    gather3_ro<<<(N_NODES + G3_NPB - 1) / G3_NPB, 64, 0, stream>>>(Q3b, off, es23, in_inv,
                                                                   gid, ro);
    normalize_out<<<N_GRAPHS, 128, 0, stream>>>(ro, out);
}